// Round 2
// baseline (659.640 us; speedup 1.0000x reference)
//
#include <hip/hip_runtime.h>
#include <math.h>

// Problem constants
#define B 64
#define D 2048
#define H 4096
#define NSEED 50000
#define KTOP 50
#define NCHUNKS 64          // topk chunks per row
#define CHUNK_SZ 782        // ceil(50000/64)

// ws layout (float offsets) — total ~5.06M floats ~= 20.3 MB (same as round 1)
#define WS_LOGITS   0                         // 64*50000 = 3,200,000
#define WS_H        3200000                   // 64*4096  = 262,144
#define WS_Q2       (WS_H + B*H)              // 64*2048  = 131,072
#define WS_PART     (WS_Q2 + B*D)             // 1,048,576 (reused by both MLP gemms)
#define WS_CVAL     (WS_PART + 1048576)       // 64*64*50 = 204,800
#define WS_CIDX     (WS_CVAL + 204800)        // 204,800 (ints)
#define WS_CM       (WS_CIDX + 204800)        // 4096
#define WS_CS       (WS_CM + 4096)            // 4096
#define WS_RM       (WS_CS + 4096)            // 64
#define WS_RS       (WS_RM + 64)              // 64
#define WS_TIDX     (WS_RS + 64)              // 3200 (ints)

struct P4 { float* p[4]; };

// ---------------------------------------------------------------------------
// MLP GEMM: C_partial[kc][64][N] = A[64][K_chunk] @ W[K_chunk][N]
// grid = nBlocks * nchunks, 256 threads. Tile: 64m x 64n, KS=32.
// ---------------------------------------------------------------------------
__global__ __launch_bounds__(256) void gemm64_kernel(
    const float* __restrict__ A, const float* __restrict__ W,
    float* __restrict__ part, int K, int N, int kcK, int nBlocks)
{
    __shared__ float As[32][68];   // [k][m], padded
    __shared__ float Bs[32][68];   // [k][n], padded

    const int tid = threadIdx.x;
    const int nb = blockIdx.x % nBlocks;
    const int kc = blockIdx.x / nBlocks;
    const int kbeg = kc * kcK;

    const int tidm = tid >> 5;          // 0..7
    const int tidn = tid & 31;          // 0..31
    const int m0 = tidm * 8;
    const int n0g = nb * 64 + tidn * 2;

    float acc[8][2];
#pragma unroll
    for (int i = 0; i < 8; ++i) { acc[i][0] = 0.f; acc[i][1] = 0.f; }

    for (int k0 = kbeg; k0 < kbeg + kcK; k0 += 32) {
        __syncthreads();
#pragma unroll
        for (int i = 0; i < 2; ++i) {
            int q = tid + i * 256;                 // 0..511
            int row = q >> 3, c = q & 7;           // A tile: 64 rows x 32 k
            float4 va = *(const float4*)(A + (size_t)row * K + k0 + c * 4);
            As[c * 4 + 0][row] = va.x; As[c * 4 + 1][row] = va.y;
            As[c * 4 + 2][row] = va.z; As[c * 4 + 3][row] = va.w;
            int wr = q >> 4, wc = q & 15;          // W tile: 32 k x 64 n
            float4 vb = *(const float4*)(W + (size_t)(k0 + wr) * N + nb * 64 + wc * 4);
            *(float4*)&Bs[wr][wc * 4] = vb;
        }
        __syncthreads();
#pragma unroll
        for (int kk = 0; kk < 32; ++kk) {
            float4 a0 = *(const float4*)&As[kk][m0];
            float4 a1 = *(const float4*)&As[kk][m0 + 4];
            float2 b = *(const float2*)&Bs[kk][tidn * 2];
            float av[8] = {a0.x, a0.y, a0.z, a0.w, a1.x, a1.y, a1.z, a1.w};
#pragma unroll
            for (int i = 0; i < 8; ++i) {
                acc[i][0] += av[i] * b.x;
                acc[i][1] += av[i] * b.y;
            }
        }
    }
#pragma unroll
    for (int i = 0; i < 8; ++i) {
        float2 v; v.x = acc[i][0]; v.y = acc[i][1];
        *(float2*)(part + (size_t)(kc * B + m0 + i) * N + n0g) = v;
    }
}

// Reduce K-chunk partials + bias (+ optional exact GELU)
__global__ void mlp_reduce_kernel(const float* __restrict__ part,
                                  const float* __restrict__ bias,
                                  float* __restrict__ out, int N, int nchunks, int gelu)
{
    int e = blockIdx.x * 256 + threadIdx.x;   // over B*N
    int b = e / N, j = e - b * N;
    float s = bias[j];
    for (int c = 0; c < nchunks; ++c)
        s += part[(size_t)(c * B + b) * N + j];
    if (gelu)
        s = 0.5f * s * (1.0f + erff(s * 0.70710678118654752f));
    out[e] = s;
}

// int64-layout hedge for vritti_types (values 0..4 -> high words all zero)
__device__ __forceinline__ bool types_is_i64(const int* t)
{
    int acc = 0;
#pragma unroll
    for (int j = 0; j < 16; ++j) acc |= t[2 * j + 1];
    return acc == 0;
}

// ---------------------------------------------------------------------------
// sims partial: part_kc[64][50000] = q2[:, kc*512:(kc+1)*512] @ seed^T slice
// grid = (196, 4), 256 threads. Tile 64m x 256n, KS=16.
// Micro: split fragments — m at {tidm*4, 32+tidm*4}, n at {tidn*4, 128+tidn*4}
// (conflict-free b128 LDS reads: 16B/lane contiguous).
// ---------------------------------------------------------------------------
__global__ __launch_bounds__(256) void sims_kernel(
    const float* __restrict__ q2, const float* __restrict__ seed, P4 parts)
{
    __shared__ float As[16][68];     // [k][m]
    __shared__ float Bs[16][260];    // [k][n]

    const int tid = threadIdx.x;
    const int nbase = blockIdx.x * 256;
    const int kbeg = blockIdx.y * 512;
    float* __restrict__ out = parts.p[blockIdx.y];

    const int tidm = tid >> 5;       // 0..7
    const int tidn = tid & 31;       // 0..31

    float acc[2][4][8];              // [mh][mi][nh*4+ni]
#pragma unroll
    for (int a = 0; a < 2; ++a)
#pragma unroll
        for (int i = 0; i < 4; ++i)
#pragma unroll
            for (int j = 0; j < 8; ++j) acc[a][i][j] = 0.f;

    const int arow = tid >> 2, ac = tid & 3;

    for (int k0 = 0; k0 < 512; k0 += 16) {
        __syncthreads();
        {   // A tile: 64 rows x 16 k (one float4/thread)
            float4 va = *(const float4*)(q2 + (size_t)arow * D + kbeg + k0 + ac * 4);
            As[ac * 4 + 0][arow] = va.x; As[ac * 4 + 1][arow] = va.y;
            As[ac * 4 + 2][arow] = va.z; As[ac * 4 + 3][arow] = va.w;
        }
#pragma unroll
        for (int i = 0; i < 4; ++i) {   // B tile: 256 n x 16 k
            int q = tid + i * 256;
            int n = q >> 2, c = q & 3;
            int ng = nbase + n;
            float4 vb = make_float4(0.f, 0.f, 0.f, 0.f);
            if (ng < NSEED)
                vb = *(const float4*)(seed + (size_t)ng * D + kbeg + k0 + c * 4);
            Bs[c * 4 + 0][n] = vb.x; Bs[c * 4 + 1][n] = vb.y;
            Bs[c * 4 + 2][n] = vb.z; Bs[c * 4 + 3][n] = vb.w;
        }
        __syncthreads();
#pragma unroll
        for (int kk = 0; kk < 16; ++kk) {
            float4 a0 = *(const float4*)&As[kk][tidm * 4];
            float4 a1 = *(const float4*)&As[kk][32 + tidm * 4];
            float4 b0 = *(const float4*)&Bs[kk][tidn * 4];
            float4 b1 = *(const float4*)&Bs[kk][128 + tidn * 4];
            float av0[4] = {a0.x, a0.y, a0.z, a0.w};
            float av1[4] = {a1.x, a1.y, a1.z, a1.w};
            float bv[8] = {b0.x, b0.y, b0.z, b0.w, b1.x, b1.y, b1.z, b1.w};
#pragma unroll
            for (int i = 0; i < 4; ++i)
#pragma unroll
                for (int j = 0; j < 8; ++j) {
                    acc[0][i][j] += av0[i] * bv[j];
                    acc[1][i][j] += av1[i] * bv[j];
                }
        }
    }

#pragma unroll
    for (int mh = 0; mh < 2; ++mh)
#pragma unroll
        for (int mi = 0; mi < 4; ++mi) {
            const int m = mh * 32 + tidm * 4 + mi;
#pragma unroll
            for (int nh = 0; nh < 2; ++nh) {
                const int n = nbase + nh * 128 + tidn * 4;
                if (n < NSEED) {
                    float4 v;
                    v.x = acc[mh][mi][nh * 4 + 0];
                    v.y = acc[mh][mi][nh * 4 + 1];
                    v.z = acc[mh][mi][nh * 4 + 2];
                    v.w = acc[mh][mi][nh * 4 + 3];
                    *(float4*)(out + (size_t)m * NSEED + n) = v;
                }
            }
        }
}

// Sum 4 K-partials + karma gate + vritti bias -> logits (in place over p[3])
__global__ __launch_bounds__(256) void finalize_kernel(
    P4 parts, const float* __restrict__ karma, const int* __restrict__ types,
    const float* __restrict__ vbias, float* __restrict__ logits)
{
    const int e = blockIdx.x * 256 + threadIdx.x;     // over 64 * 12500 float4s
    const int row = e / (NSEED / 4);
    const int f = e - row * (NSEED / 4);
    const size_t off = (size_t)row * NSEED + f * 4;
    const int n = f * 4;

    float4 s0 = *(const float4*)(parts.p[0] + off);
    float4 s1 = *(const float4*)(parts.p[1] + off);
    float4 s2 = *(const float4*)(parts.p[2] + off);
    float4 s3 = *(const float4*)(parts.p[3] + off);
    float v[4] = {s0.x + s1.x + s2.x + s3.x, s0.y + s1.y + s2.y + s3.y,
                  s0.z + s1.z + s2.z + s3.z, s0.w + s1.w + s2.w + s3.w};

    const bool i64 = types_is_i64(types);
    float4 o;
    float* po = &o.x;
#pragma unroll
    for (int j = 0; j < 4; ++j) {
        float ka = karma[n + j];
        float gate = 1.0f / (1.0f + expf(-(ka + 0.3f) * 10.0f));
        int ty = i64 ? types[2 * (n + j)] : types[n + j];
        po[j] = v[j] * gate + vbias[ty];
    }
    *(float4*)(logits + off) = o;
}

// ---------------------------------------------------------------------------
// Per-(row,chunk): online softmax partial (m,s) + exact chunk top-50.
// grid = 64 rows * 64 chunks, 64 threads (1 wave).
// ---------------------------------------------------------------------------
__global__ __launch_bounds__(64) void chunk_topk_kernel(
    const float* __restrict__ logits,
    float* __restrict__ chunk_m, float* __restrict__ chunk_s,
    float* __restrict__ cand_val, int* __restrict__ cand_idx)
{
    const int bid = blockIdx.x;
    const int row = bid >> 6, chunk = bid & 63;
    const int start = chunk * CHUNK_SZ;
    const int end = min(start + CHUNK_SZ, NSEED);
    const int lane = threadIdx.x;
    const float* Lrow = logits + (size_t)row * NSEED;

    float v[13];
#pragma unroll
    for (int j = 0; j < 13; ++j) {
        int e = start + lane + j * 64;
        v[j] = (e < end) ? Lrow[e] : -INFINITY;
    }

    // online (m, s) partial: s = sum exp(2*(l - m))
    float m = v[0];
#pragma unroll
    for (int j = 1; j < 13; ++j) m = fmaxf(m, v[j]);
    float s = 0.f;
#pragma unroll
    for (int j = 0; j < 13; ++j) s += expf(2.f * (v[j] - m));
#pragma unroll
    for (int d = 1; d < 64; d <<= 1) {
        float mo = __shfl_xor(m, d);
        float so = __shfl_xor(s, d);
        float nm = fmaxf(m, mo);
        s = s * expf(2.f * (m - nm)) + so * expf(2.f * (mo - nm));
        m = nm;
    }
    if (lane == 0) { chunk_m[bid] = m; chunk_s[bid] = s; }

    // chunk top-50 via 50 wave-argmax iterations (lower index wins ties)
    for (int it = 0; it < KTOP; ++it) {
        float bv = v[0]; int bj = 0;
#pragma unroll
        for (int j = 1; j < 13; ++j)
            if (v[j] > bv) { bv = v[j]; bj = j; }
        int bi = start + lane + bj * 64;
#pragma unroll
        for (int d = 1; d < 64; d <<= 1) {
            float ov = __shfl_xor(bv, d);
            int oi = __shfl_xor(bi, d);
            if (ov > bv || (ov == bv && oi < bi)) { bv = ov; bi = oi; }
        }
        if (lane == 0) {
            cand_val[bid * KTOP + it] = bv;
            cand_idx[bid * KTOP + it] = bi;
        }
#pragma unroll
        for (int j = 0; j < 13; ++j)
            if (start + lane + j * 64 == bi) v[j] = -INFINITY;
    }
}

// ---------------------------------------------------------------------------
// Per-row merge: 64 (m,s) partials -> (M, 1/S); 3200 candidates -> top-50.
// ---------------------------------------------------------------------------
__global__ __launch_bounds__(256) void merge_topk_kernel(
    const float* __restrict__ chunk_m, const float* __restrict__ chunk_s,
    const float* __restrict__ cand_val, const int* __restrict__ cand_idx,
    float* __restrict__ row_M, float* __restrict__ row_rS,
    float* __restrict__ out_idx_f, int* __restrict__ topk_idx)
{
    const int row = blockIdx.x;
    const int tid = threadIdx.x;
    const int lane = tid & 63, wave = tid >> 6;
    __shared__ float rv[4];
    __shared__ int ri[4];

    if (wave == 0) {
        float m = chunk_m[row * 64 + lane];
        float s = chunk_s[row * 64 + lane];
#pragma unroll
        for (int d = 1; d < 64; d <<= 1) {
            float mo = __shfl_xor(m, d);
            float so = __shfl_xor(s, d);
            float nm = fmaxf(m, mo);
            s = s * expf(2.f * (m - nm)) + so * expf(2.f * (mo - nm));
            m = nm;
        }
        if (lane == 0) { row_M[row] = m; row_rS[row] = 1.0f / s; }
    }

    float v[13]; int ix[13];
#pragma unroll
    for (int j = 0; j < 13; ++j) {
        int e = tid + j * 256;
        if (e < NCHUNKS * KTOP) {
            v[j] = cand_val[row * (NCHUNKS * KTOP) + e];
            ix[j] = cand_idx[row * (NCHUNKS * KTOP) + e];
        } else { v[j] = -INFINITY; ix[j] = 0x7fffffff; }
    }

    for (int it = 0; it < KTOP; ++it) {
        float bv = v[0]; int bi = ix[0];
#pragma unroll
        for (int j = 1; j < 13; ++j)
            if (v[j] > bv || (v[j] == bv && ix[j] < bi)) { bv = v[j]; bi = ix[j]; }
#pragma unroll
        for (int d = 1; d < 64; d <<= 1) {
            float ov = __shfl_xor(bv, d);
            int oi = __shfl_xor(bi, d);
            if (ov > bv || (ov == bv && oi < bi)) { bv = ov; bi = oi; }
        }
        if (lane == 0) { rv[wave] = bv; ri[wave] = bi; }
        __syncthreads();
        float wv = rv[0]; int wi = ri[0];
#pragma unroll
        for (int w = 1; w < 4; ++w)
            if (rv[w] > wv || (rv[w] == wv && ri[w] < wi)) { wv = rv[w]; wi = ri[w]; }
        __syncthreads();
        if (tid == 0) {
            out_idx_f[row * KTOP + it] = (float)wi;
            topk_idx[row * KTOP + it] = wi;
        }
#pragma unroll
        for (int j = 0; j < 13; ++j)
            if (ix[j] == wi) v[j] = -INFINITY;
    }
}

// attention weights: w = exp(2*(l - M)) / S
__global__ void weights_kernel(const float* __restrict__ logits,
                               const float* __restrict__ row_M,
                               const float* __restrict__ row_rS,
                               float* __restrict__ attn)
{
    const int row = blockIdx.y;
    const int f = blockIdx.x * 256 + threadIdx.x;
    if (f >= NSEED / 4) return;
    const float M = row_M[row], rS = row_rS[row];
    float4 l = ((const float4*)(logits + (size_t)row * NSEED))[f];
    float4 w;
    w.x = expf(2.f * (l.x - M)) * rS;
    w.y = expf(2.f * (l.y - M)) * rS;
    w.z = expf(2.f * (l.z - M)) * rS;
    w.w = expf(2.f * (l.w - M)) * rS;
    ((float4*)(attn + (size_t)row * NSEED))[f] = w;
}

// chitta gather: 2048 floats per (row,k)
__global__ void gather_kernel(const float* __restrict__ seed,
                              const int* __restrict__ topk_idx,
                              float* __restrict__ chitta)
{
    const int k = blockIdx.x, row = blockIdx.y;
    const int idx = topk_idx[row * KTOP + k];
    const float4* src = (const float4*)(seed + (size_t)idx * D);
    float4* dst = (float4*)(chitta + (size_t)(row * KTOP + k) * D);
#pragma unroll
    for (int j = 0; j < 2; ++j)
        dst[threadIdx.x + j * 256] = src[threadIdx.x + j * 256];
}

extern "C" void kernel_launch(void* const* d_in, const int* in_sizes, int n_in,
                              void* d_out, int out_size, void* d_ws, size_t ws_size,
                              hipStream_t stream)
{
    const float* query = (const float*)d_in[0];
    const int*   types = (const int*)d_in[1];
    const float* seed  = (const float*)d_in[2];
    const float* karma = (const float*)d_in[3];
    const float* vbias = (const float*)d_in[4];
    const float* W1    = (const float*)d_in[5];
    const float* b1    = (const float*)d_in[6];
    const float* W2    = (const float*)d_in[7];
    const float* b2    = (const float*)d_in[8];

    float* ws = (float*)d_ws;
    float* logits = ws + WS_LOGITS;
    float* h      = ws + WS_H;
    float* q2     = ws + WS_Q2;
    float* part   = ws + WS_PART;
    float* cval   = ws + WS_CVAL;
    int*   cidx   = (int*)(ws + WS_CIDX);
    float* cm     = ws + WS_CM;
    float* cs     = ws + WS_CS;
    float* rM     = ws + WS_RM;
    float* rS     = ws + WS_RS;
    int*   tidx   = (int*)(ws + WS_TIDX);

    float* outv   = (float*)d_out;
    float* chitta = outv;                                   // [64][50][2048]
    float* attn   = outv + (size_t)B * KTOP * D;            // [64][50000]
    float* oidxf  = attn + (size_t)B * NSEED;               // [64][50] as float

    // sims partials live in regions that are overwritten only later:
    // p0,p1 in chitta (26.2 MB >= 2*12.8), p2 in attn, p3 in ws logits
    // (finalize sums into p3's location = logits, element-wise in place).
    P4 parts;
    parts.p[0] = chitta;
    parts.p[1] = chitta + (size_t)B * NSEED;
    parts.p[2] = attn;
    parts.p[3] = logits;

    // MLP layer 1: 64 n-blocks x 4 k-chunks (K chunk = 512)
    gemm64_kernel<<<256, 256, 0, stream>>>(query, W1, part, D, H, 512, H / 64);
    mlp_reduce_kernel<<<(B * H) / 256, 256, 0, stream>>>(part, b1, h, H, 4, 1);
    // MLP layer 2: 32 n-blocks x 8 k-chunks (K chunk = 512)
    gemm64_kernel<<<256, 256, 0, stream>>>(h, W2, part, H, D, 512, D / 64);
    mlp_reduce_kernel<<<(B * D) / 256, 256, 0, stream>>>(part, b2, q2, D, 8, 0);
    // similarity partials: 196 n-blocks x 4 K-chunks = 784 blocks
    sims_kernel<<<dim3(196, 4), 256, 0, stream>>>(q2, seed, parts);
    // sum partials + gate + bias -> logits
    finalize_kernel<<<(B * (NSEED / 4)) / 256, 256, 0, stream>>>(parts, karma, types, vbias, logits);
    // per-chunk stats + top-50 candidates
    chunk_topk_kernel<<<B * NCHUNKS, 64, 0, stream>>>(logits, cm, cs, cval, cidx);
    // per-row merge -> (M, 1/S) + final sorted top-50 indices
    merge_topk_kernel<<<B, 256, 0, stream>>>(cm, cs, cval, cidx, rM, rS, oidxf, tidx);
    // full attention weights
    weights_kernel<<<dim3((NSEED / 4 + 255) / 256, B), 256, 0, stream>>>(logits, rM, rS, attn);
    // retrieved embeddings
    gather_kernel<<<dim3(KTOP, B), 256, 0, stream>>>(seed, tidx, chitta);
}

// Round 4
// 500.441 us; speedup vs baseline: 1.3181x; 1.3181x over previous
//
#include <hip/hip_runtime.h>
#include <math.h>

// Problem constants
#define B 64
#define D 2048
#define H 4096
#define NSEED 50000
#define KTOP 50
#define NCAND 128           // rescored candidates per row
#define NCHUNKS 64          // topk chunks per row
#define CHUNK_SZ 782        // ceil(50000/64)

// ws layout (float offsets)
#define WS_LOGITS   0                         // 64*50000 = 3,200,000
#define WS_H        3200000                   // 64*4096  = 262,144
#define WS_Q2       (WS_H + B*H)              // 64*2048  = 131,072
#define WS_PART     (WS_Q2 + B*D)             // 1,048,576 (MLP partials; later q2h/l + cand/rvals)
#define WS_CVAL     (WS_PART + 1048576)       // 64*64*50 = 204,800
#define WS_CIDX     (WS_CVAL + 204800)        // 204,800 (ints)
#define WS_CM       (WS_CIDX + 204800)        // 4096
#define WS_CS       (WS_CM + 4096)            // 4096
#define WS_RM       (WS_CS + 4096)            // 64
#define WS_RS       (WS_RM + 64)              // 64
// sub-allocations inside the (sequentially freed) PART region:
#define WSP_Q2H     0                         // 2*131072 ushorts = 131,072 floats
#define WSP_CAND    200000                    // 64*128 ints
#define WSP_RVAL    220000                    // 64*128 floats
#define WSP_TIDX    240000                    // 64*50 ints

typedef short s16x8 __attribute__((ext_vector_type(8)));
typedef float f32x4 __attribute__((ext_vector_type(4)));

// ---------------------------------------------------------------------------
// bf16 split helpers: x ~= hi + lo, both RNE bf16.
// ---------------------------------------------------------------------------
__device__ __forceinline__ unsigned short bf16_rne(float x)
{
    unsigned int b = __float_as_uint(x);
    b += 0x7FFFu + ((b >> 16) & 1u);
    return (unsigned short)(b >> 16);
}
__device__ __forceinline__ float bf16_tof(unsigned short h)
{
    return __uint_as_float(((unsigned int)h) << 16);
}

// ---------------------------------------------------------------------------
// MLP GEMM: C_partial[kc][64][N] = A[64][K_chunk] @ W[K_chunk][N]
// ---------------------------------------------------------------------------
__global__ __launch_bounds__(256) void gemm64_kernel(
    const float* __restrict__ A, const float* __restrict__ W,
    float* __restrict__ part, int K, int N, int kcK, int nBlocks)
{
    __shared__ float As[32][68];   // [k][m], padded
    __shared__ float Bs[32][68];   // [k][n], padded

    const int tid = threadIdx.x;
    const int nb = blockIdx.x % nBlocks;
    const int kc = blockIdx.x / nBlocks;
    const int kbeg = kc * kcK;

    const int tidm = tid >> 5;          // 0..7
    const int tidn = tid & 31;          // 0..31
    const int m0 = tidm * 8;
    const int n0g = nb * 64 + tidn * 2;

    float acc[8][2];
#pragma unroll
    for (int i = 0; i < 8; ++i) { acc[i][0] = 0.f; acc[i][1] = 0.f; }

    for (int k0 = kbeg; k0 < kbeg + kcK; k0 += 32) {
        __syncthreads();
#pragma unroll
        for (int i = 0; i < 2; ++i) {
            int q = tid + i * 256;                 // 0..511
            int row = q >> 3, c = q & 7;           // A tile: 64 rows x 32 k
            float4 va = *(const float4*)(A + (size_t)row * K + k0 + c * 4);
            As[c * 4 + 0][row] = va.x; As[c * 4 + 1][row] = va.y;
            As[c * 4 + 2][row] = va.z; As[c * 4 + 3][row] = va.w;
            int wr = q >> 4, wc = q & 15;          // W tile: 32 k x 64 n
            float4 vb = *(const float4*)(W + (size_t)(k0 + wr) * N + nb * 64 + wc * 4);
            *(float4*)&Bs[wr][wc * 4] = vb;
        }
        __syncthreads();
#pragma unroll
        for (int kk = 0; kk < 32; ++kk) {
            float4 a0 = *(const float4*)&As[kk][m0];
            float4 a1 = *(const float4*)&As[kk][m0 + 4];
            float2 b = *(const float2*)&Bs[kk][tidn * 2];
            float av[8] = {a0.x, a0.y, a0.z, a0.w, a1.x, a1.y, a1.z, a1.w};
#pragma unroll
            for (int i = 0; i < 8; ++i) {
                acc[i][0] += av[i] * b.x;
                acc[i][1] += av[i] * b.y;
            }
        }
    }
#pragma unroll
    for (int i = 0; i < 8; ++i) {
        float2 v; v.x = acc[i][0]; v.y = acc[i][1];
        *(float2*)(part + (size_t)(kc * B + m0 + i) * N + n0g) = v;
    }
}

// Reduce K-chunk partials + bias (+ optional exact GELU)
__global__ void mlp_reduce_kernel(const float* __restrict__ part,
                                  const float* __restrict__ bias,
                                  float* __restrict__ out, int N, int nchunks, int gelu)
{
    int e = blockIdx.x * 256 + threadIdx.x;   // over B*N
    int b = e / N, j = e - b * N;
    float s = bias[j];
    for (int c = 0; c < nchunks; ++c)
        s += part[(size_t)(c * B + b) * N + j];
    if (gelu)
        s = 0.5f * s * (1.0f + erff(s * 0.70710678118654752f));
    out[e] = s;
}

// q2 fp32 -> bf16 hi/lo split (4 elems/thread)
__global__ __launch_bounds__(256) void convert_q2_kernel(
    const float* __restrict__ q2,
    unsigned short* __restrict__ q2h, unsigned short* __restrict__ q2l)
{
    const int e = blockIdx.x * 256 + threadIdx.x;   // over B*D/4
    float4 v = ((const float4*)q2)[e];
    float xs[4] = {v.x, v.y, v.z, v.w};
    ushort4 hv, lv;
    unsigned short* ph = &hv.x;
    unsigned short* pl = &lv.x;
#pragma unroll
    for (int j = 0; j < 4; ++j) {
        unsigned short h = bf16_rne(xs[j]);
        ph[j] = h;
        pl[j] = bf16_rne(xs[j] - bf16_tof(h));
    }
    ((ushort4*)q2h)[e] = hv;
    ((ushort4*)q2l)[e] = lv;
}

// int64-layout hedge for vritti_types (values 0..4 -> high words all zero)
__device__ __forceinline__ bool types_is_i64(const int* t)
{
    int acc = 0;
#pragma unroll
    for (int j = 0; j < 16; ++j) acc |= t[2 * j + 1];
    return acc == 0;
}

// ---------------------------------------------------------------------------
// sims via split-bf16 MFMA: logits = (q2 @ seed^T)*gate + vbias[type]
// grid = 782 (64-col tiles), 256 threads = 4 waves; wave w owns n-tile w.
// A (q2 hi/lo) staged via LDS (shared by all waves); B (seed) loaded
// DIRECTLY into registers per lane (each seed element read exactly once),
// split to bf16 hi/lo in-register. 3 MFMAs per product (AhBh+AlBh+AhBl);
// residual ~1e-5 is handled by the exact rescore of top-NCAND candidates.
// ---------------------------------------------------------------------------
__global__ __launch_bounds__(256) void sims_mfma_kernel(
    const unsigned short* __restrict__ q2h, const unsigned short* __restrict__ q2l,
    const float* __restrict__ seed,
    const float* __restrict__ karma, const int* __restrict__ types,
    const float* __restrict__ vbias, float* __restrict__ logits)
{
    __shared__ __align__(16) unsigned short Ash[64][40];
    __shared__ __align__(16) unsigned short Asl[64][40];

    const int tid = threadIdx.x;
    const int n0 = blockIdx.x * 64;
    const int lane = tid & 63;
    const int wv  = tid >> 6;       // 0..3: n-tile of this wave
    const int l15 = lane & 15;
    const int lg  = lane >> 4;      // k-group 0..3

    const int srow = tid >> 2;      // A staging row 0..63
    const int sks  = tid & 3;       // A staging k-segment (8 elems)

    const int nrow = n0 + wv * 16 + l15;            // seed row this lane owns
    const bool nvalid = nrow < NSEED;
    const float* brow = seed + (size_t)nrow * D + 8 * lg;

    f32x4 acc[4];
#pragma unroll
    for (int t = 0; t < 4; ++t) acc[t] = (f32x4){0.f, 0.f, 0.f, 0.f};

    for (int k0 = 0; k0 < D; k0 += 32) {
        // B: direct global->reg (issued early; no LDS)
        float4 f0 = make_float4(0.f, 0.f, 0.f, 0.f);
        float4 f1 = f0;
        if (nvalid) {
            f0 = *(const float4*)(brow + k0);
            f1 = *(const float4*)(brow + k0 + 4);
        }
        __syncthreads();   // WAR: previous iteration's frag reads done
        {   // A stage: q2 hi/lo bf16, 16 B per thread each
            const size_t off = (size_t)srow * D + k0 + 8 * sks;
            *(s16x8*)&Ash[srow][8 * sks] = *(const s16x8*)(q2h + off);
            *(s16x8*)&Asl[srow][8 * sks] = *(const s16x8*)(q2l + off);
        }
        __syncthreads();

        // convert B to hi/lo bf16 in registers
        s16x8 bh, bl;
        {
            float xs[8] = {f0.x, f0.y, f0.z, f0.w, f1.x, f1.y, f1.z, f1.w};
#pragma unroll
            for (int j = 0; j < 8; ++j) {
                unsigned short hu = bf16_rne(xs[j]);
                bh[j] = (short)hu;
                bl[j] = (short)bf16_rne(xs[j] - bf16_tof(hu));
            }
        }
#pragma unroll
        for (int t = 0; t < 4; ++t) {
            s16x8 ah = *(const s16x8*)&Ash[t * 16 + l15][8 * lg];
            s16x8 al = *(const s16x8*)&Asl[t * 16 + l15][8 * lg];
            acc[t] = __builtin_amdgcn_mfma_f32_16x16x32_bf16(ah, bh, acc[t], 0, 0, 0);
            acc[t] = __builtin_amdgcn_mfma_f32_16x16x32_bf16(al, bh, acc[t], 0, 0, 0);
            acc[t] = __builtin_amdgcn_mfma_f32_16x16x32_bf16(ah, bl, acc[t], 0, 0, 0);
        }
    }

    // epilogue: gate + vritti bias. D layout: col=lane&15, row=4*lg+reg.
    if (nvalid) {
        const bool i64 = types_is_i64(types);
        float ka = karma[nrow];
        float gate = 1.0f / (1.0f + expf(-(ka + 0.3f) * 10.0f));
        int ty = i64 ? types[2 * nrow] : types[nrow];
        float bias = vbias[ty];
#pragma unroll
        for (int t = 0; t < 4; ++t) {
#pragma unroll
            for (int r = 0; r < 4; ++r) {
                int m = t * 16 + lg * 4 + r;
                logits[(size_t)m * NSEED + nrow] = acc[t][r] * gate + bias;
            }
        }
    }
}

// ---------------------------------------------------------------------------
// Per-(row,chunk): online softmax partial (m,s) + exact chunk top-50.
// grid = 64 rows * 64 chunks, 64 threads (1 wave).
// ---------------------------------------------------------------------------
__global__ __launch_bounds__(64) void chunk_topk_kernel(
    const float* __restrict__ logits,
    float* __restrict__ chunk_m, float* __restrict__ chunk_s,
    float* __restrict__ cand_val, int* __restrict__ cand_idx)
{
    const int bid = blockIdx.x;
    const int row = bid >> 6, chunk = bid & 63;
    const int start = chunk * CHUNK_SZ;
    const int end = min(start + CHUNK_SZ, NSEED);
    const int lane = threadIdx.x;
    const float* Lrow = logits + (size_t)row * NSEED;

    float v[13];
#pragma unroll
    for (int j = 0; j < 13; ++j) {
        int e = start + lane + j * 64;
        v[j] = (e < end) ? Lrow[e] : -INFINITY;
    }

    // online (m, s) partial: s = sum exp(2*(l - m))
    float m = v[0];
#pragma unroll
    for (int j = 1; j < 13; ++j) m = fmaxf(m, v[j]);
    float s = 0.f;
#pragma unroll
    for (int j = 0; j < 13; ++j) s += expf(2.f * (v[j] - m));
#pragma unroll
    for (int d = 1; d < 64; d <<= 1) {
        float mo = __shfl_xor(m, d);
        float so = __shfl_xor(s, d);
        float nm = fmaxf(m, mo);
        s = s * expf(2.f * (m - nm)) + so * expf(2.f * (mo - nm));
        m = nm;
    }
    if (lane == 0) { chunk_m[bid] = m; chunk_s[bid] = s; }

    // chunk top-50 via 50 wave-argmax iterations (lower index wins ties)
    for (int it = 0; it < KTOP; ++it) {
        float bv = v[0]; int bj = 0;
#pragma unroll
        for (int j = 1; j < 13; ++j)
            if (v[j] > bv) { bv = v[j]; bj = j; }
        int bi = start + lane + bj * 64;
#pragma unroll
        for (int d = 1; d < 64; d <<= 1) {
            float ov = __shfl_xor(bv, d);
            int oi = __shfl_xor(bi, d);
            if (ov > bv || (ov == bv && oi < bi)) { bv = ov; bi = oi; }
        }
        if (lane == 0) {
            cand_val[bid * KTOP + it] = bv;
            cand_idx[bid * KTOP + it] = bi;
        }
#pragma unroll
        for (int j = 0; j < 13; ++j)
            if (start + lane + j * 64 == bi) v[j] = -INFINITY;
    }
}

// ---------------------------------------------------------------------------
// Per-row merge: 64 (m,s) partials -> (M, 1/S); 3200 candidates -> top-NCAND
// candidate indices (by MFMA logit; candidate set, not final order).
// ---------------------------------------------------------------------------
__global__ __launch_bounds__(256) void merge_topk_kernel(
    const float* __restrict__ chunk_m, const float* __restrict__ chunk_s,
    const float* __restrict__ cand_val, const int* __restrict__ cand_idx,
    float* __restrict__ row_M, float* __restrict__ row_rS,
    int* __restrict__ cand2)
{
    const int row = blockIdx.x;
    const int tid = threadIdx.x;
    const int lane = tid & 63, wave = tid >> 6;
    __shared__ float rv[4];
    __shared__ int ri[4];

    if (wave == 0) {
        float m = chunk_m[row * 64 + lane];
        float s = chunk_s[row * 64 + lane];
#pragma unroll
        for (int d = 1; d < 64; d <<= 1) {
            float mo = __shfl_xor(m, d);
            float so = __shfl_xor(s, d);
            float nm = fmaxf(m, mo);
            s = s * expf(2.f * (m - nm)) + so * expf(2.f * (mo - nm));
            m = nm;
        }
        if (lane == 0) { row_M[row] = m; row_rS[row] = 1.0f / s; }
    }

    float v[13]; int ix[13];
#pragma unroll
    for (int j = 0; j < 13; ++j) {
        int e = tid + j * 256;
        if (e < NCHUNKS * KTOP) {
            v[j] = cand_val[row * (NCHUNKS * KTOP) + e];
            ix[j] = cand_idx[row * (NCHUNKS * KTOP) + e];
        } else { v[j] = -INFINITY; ix[j] = 0x7fffffff; }
    }

    for (int it = 0; it < NCAND; ++it) {
        float bv = v[0]; int bi = ix[0];
#pragma unroll
        for (int j = 1; j < 13; ++j)
            if (v[j] > bv || (v[j] == bv && ix[j] < bi)) { bv = v[j]; bi = ix[j]; }
#pragma unroll
        for (int d = 1; d < 64; d <<= 1) {
            float ov = __shfl_xor(bv, d);
            int oi = __shfl_xor(bi, d);
            if (ov > bv || (ov == bv && oi < bi)) { bv = ov; bi = oi; }
        }
        if (lane == 0) { rv[wave] = bv; ri[wave] = bi; }
        __syncthreads();
        float wv = rv[0]; int wi = ri[0];
#pragma unroll
        for (int w = 1; w < 4; ++w)
            if (rv[w] > wv || (rv[w] == wv && ri[w] < wi)) { wv = rv[w]; wi = ri[w]; }
        __syncthreads();
        if (tid == 0) cand2[row * NCAND + it] = wi;
#pragma unroll
        for (int j = 0; j < 13; ++j)
            if (ix[j] == wi) v[j] = -INFINITY;
    }
}

// ---------------------------------------------------------------------------
// Exact rescore of candidates: fp64 dot(q2[row], seed[idx]) + fp32 gate/bias.
// grid = (NCAND/4, 64 rows), 256 threads = 4 waves (one candidate per wave).
// ---------------------------------------------------------------------------
__global__ __launch_bounds__(256) void rescore_kernel(
    const float* __restrict__ q2, const float* __restrict__ seed,
    const float* __restrict__ karma, const int* __restrict__ types,
    const float* __restrict__ vbias, const int* __restrict__ cand2,
    float* __restrict__ rvals)
{
    const int row = blockIdx.y;
    const int wv = threadIdx.x >> 6, lane = threadIdx.x & 63;
    const int ci = blockIdx.x * 4 + wv;             // 0..NCAND-1
    const int idx = cand2[row * NCAND + ci];
    const float* qrow = q2 + (size_t)row * D;
    const float* srow = seed + (size_t)idx * D;

    double s = 0.0;
#pragma unroll
    for (int i = 0; i < 8; ++i) {
        float4 a = *(const float4*)(qrow + lane * 4 + i * 256);
        float4 b = *(const float4*)(srow + lane * 4 + i * 256);
        s += (double)a.x * (double)b.x + (double)a.y * (double)b.y
           + (double)a.z * (double)b.z + (double)a.w * (double)b.w;
    }
#pragma unroll
    for (int d = 1; d < 64; d <<= 1) s += __shfl_xor(s, d);

    if (lane == 0) {
        float ka = karma[idx];
        float gate = 1.0f / (1.0f + expf(-(ka + 0.3f) * 10.0f));
        bool i64 = types_is_i64(types);
        int ty = i64 ? types[2 * idx] : types[idx];
        rvals[row * NCAND + ci] = (float)s * gate + vbias[ty];
    }
}

// ---------------------------------------------------------------------------
// Final per-row top-50 (sorted desc, lower index on ties) from NCAND rescored.
// grid = 64, 64 threads (1 wave).
// ---------------------------------------------------------------------------
__global__ __launch_bounds__(64) void final50_kernel(
    const float* __restrict__ rvals, const int* __restrict__ cand2,
    float* __restrict__ out_idx_f, int* __restrict__ topk_idx)
{
    const int row = blockIdx.x;
    const int lane = threadIdx.x;

    float v[2]; int ix[2];
#pragma unroll
    for (int j = 0; j < 2; ++j) {
        int e = lane + j * 64;
        v[j] = rvals[row * NCAND + e];
        ix[j] = cand2[row * NCAND + e];
    }

    for (int it = 0; it < KTOP; ++it) {
        float bv = v[0]; int bi = ix[0];
        if (v[1] > bv || (v[1] == bv && ix[1] < bi)) { bv = v[1]; bi = ix[1]; }
#pragma unroll
        for (int d = 1; d < 64; d <<= 1) {
            float ov = __shfl_xor(bv, d);
            int oi = __shfl_xor(bi, d);
            if (ov > bv || (ov == bv && oi < bi)) { bv = ov; bi = oi; }
        }
        if (lane == 0) {
            out_idx_f[row * KTOP + it] = (float)bi;
            topk_idx[row * KTOP + it] = bi;
        }
#pragma unroll
        for (int j = 0; j < 2; ++j)
            if (ix[j] == bi) v[j] = -INFINITY;
    }
}

// attention weights: w = exp(2*(l - M)) / S
__global__ void weights_kernel(const float* __restrict__ logits,
                               const float* __restrict__ row_M,
                               const float* __restrict__ row_rS,
                               float* __restrict__ attn)
{
    const int row = blockIdx.y;
    const int f = blockIdx.x * 256 + threadIdx.x;
    if (f >= NSEED / 4) return;
    const float M = row_M[row], rS = row_rS[row];
    float4 l = ((const float4*)(logits + (size_t)row * NSEED))[f];
    float4 w;
    w.x = expf(2.f * (l.x - M)) * rS;
    w.y = expf(2.f * (l.y - M)) * rS;
    w.z = expf(2.f * (l.z - M)) * rS;
    w.w = expf(2.f * (l.w - M)) * rS;
    ((float4*)(attn + (size_t)row * NSEED))[f] = w;
}

// chitta gather: 2048 floats per (row,k)
__global__ void gather_kernel(const float* __restrict__ seed,
                              const int* __restrict__ topk_idx,
                              float* __restrict__ chitta)
{
    const int k = blockIdx.x, row = blockIdx.y;
    const int idx = topk_idx[row * KTOP + k];
    const float4* src = (const float4*)(seed + (size_t)idx * D);
    float4* dst = (float4*)(chitta + (size_t)(row * KTOP + k) * D);
#pragma unroll
    for (int j = 0; j < 2; ++j)
        dst[threadIdx.x + j * 256] = src[threadIdx.x + j * 256];
}

extern "C" void kernel_launch(void* const* d_in, const int* in_sizes, int n_in,
                              void* d_out, int out_size, void* d_ws, size_t ws_size,
                              hipStream_t stream)
{
    const float* query = (const float*)d_in[0];
    const int*   types = (const int*)d_in[1];
    const float* seed  = (const float*)d_in[2];
    const float* karma = (const float*)d_in[3];
    const float* vbias = (const float*)d_in[4];
    const float* W1    = (const float*)d_in[5];
    const float* b1    = (const float*)d_in[6];
    const float* W2    = (const float*)d_in[7];
    const float* b2    = (const float*)d_in[8];

    float* ws = (float*)d_ws;
    float* logits = ws + WS_LOGITS;
    float* h      = ws + WS_H;
    float* q2     = ws + WS_Q2;
    float* part   = ws + WS_PART;
    float* cval   = ws + WS_CVAL;
    int*   cidx   = (int*)(ws + WS_CIDX);
    float* cm     = ws + WS_CM;
    float* cs     = ws + WS_CS;
    float* rM     = ws + WS_RM;
    float* rS     = ws + WS_RS;

    // sub-allocations inside PART (free after mlp_reduce layer 2):
    unsigned short* q2h = (unsigned short*)(part + WSP_Q2H);  // 64*2048 ushorts
    unsigned short* q2l = q2h + (size_t)B * D;
    int*   cand2 = (int*)(part + WSP_CAND);                   // 64*128
    float* rvals = part + WSP_RVAL;                           // 64*128
    int*   tidx  = (int*)(part + WSP_TIDX);                   // 64*50

    float* outv   = (float*)d_out;
    float* chitta = outv;                                   // [64][50][2048]
    float* attn   = outv + (size_t)B * KTOP * D;            // [64][50000]
    float* oidxf  = attn + (size_t)B * NSEED;               // [64][50] as float

    // MLP layer 1: 64 n-blocks x 4 k-chunks (K chunk = 512)
    gemm64_kernel<<<256, 256, 0, stream>>>(query, W1, part, D, H, 512, H / 64);
    mlp_reduce_kernel<<<(B * H) / 256, 256, 0, stream>>>(part, b1, h, H, 4, 1);
    // MLP layer 2: 32 n-blocks x 8 k-chunks (K chunk = 512)
    gemm64_kernel<<<256, 256, 0, stream>>>(h, W2, part, H, D, 512, D / 64);
    mlp_reduce_kernel<<<(B * D) / 256, 256, 0, stream>>>(part, b2, q2, D, 8, 0);
    // split q2 into bf16 hi/lo
    convert_q2_kernel<<<(B * D / 4) / 256, 256, 0, stream>>>(q2, q2h, q2l);
    // similarity + gate + bias -> logits (split-bf16 MFMA, B direct-to-reg)
    sims_mfma_kernel<<<(NSEED + 63) / 64, 256, 0, stream>>>(q2h, q2l, seed, karma, types, vbias, logits);
    // per-chunk stats + top-50 candidates
    chunk_topk_kernel<<<B * NCHUNKS, 64, 0, stream>>>(logits, cm, cs, cval, cidx);
    // per-row merge -> (M, 1/S) + top-NCAND candidate set
    merge_topk_kernel<<<B, 256, 0, stream>>>(cm, cs, cval, cidx, rM, rS, cand2);
    // exact fp64 rescore of candidates
    rescore_kernel<<<dim3(NCAND / 4, B), 256, 0, stream>>>(q2, seed, karma, types, vbias, cand2, rvals);
    // final sorted top-50 indices
    final50_kernel<<<B, 64, 0, stream>>>(rvals, cand2, oidxf, tidx);
    // full attention weights
    weights_kernel<<<dim3((NSEED / 4 + 255) / 256, B), 256, 0, stream>>>(logits, rM, rS, attn);
    // retrieved embeddings
    gather_kernel<<<dim3(KTOP, B), 256, 0, stream>>>(seed, tidx, chitta);
}

// Round 5
// 446.016 us; speedup vs baseline: 1.4790x; 1.1220x over previous
//
#include <hip/hip_runtime.h>
#include <math.h>

// Problem constants
#define B 64
#define D 2048
#define H 4096
#define NSEED 50000
#define KTOP 50
#define NCAND 64            // rescored candidates per row
#define CEMIT 64            // candidates emitted per chunk
#define NCHUNKS 64          // topk chunks per row
#define CHUNK_SZ 782        // ceil(50000/64)

// ws layout (float offsets)
#define WS_LOGITS   0                         // 64*50000 = 3,200,000
#define WS_H        3200000                   // 64*4096  = 262,144
#define WS_Q2       (WS_H + B*H)              // 64*2048  = 131,072
#define WS_PART     (WS_Q2 + B*D)             // 1,048,576 (MLP partials; later q2h/l + cand/rvals)
#define WS_CVAL     (WS_PART + 1048576)       // 64*64*64 = 262,144
#define WS_CIDX     (WS_CVAL + 262144)        // 262,144 (ints)
#define WS_CM       (WS_CIDX + 262144)        // 4096
#define WS_CS       (WS_CM + 4096)            // 4096
#define WS_RM       (WS_CS + 4096)            // 64
#define WS_RS       (WS_RM + 64)              // 64
// sub-allocations inside the (sequentially freed) PART region:
#define WSP_Q2H     0                         // 2*131072 ushorts = 131,072 floats
#define WSP_CAND    200000                    // 64*64 ints
#define WSP_RVAL    220000                    // 64*64 floats
#define WSP_TIDX    240000                    // 64*50 ints

typedef short s16x8 __attribute__((ext_vector_type(8)));
typedef float f32x4 __attribute__((ext_vector_type(4)));

// ---------------------------------------------------------------------------
// bf16 split helpers: x ~= hi + lo, both RNE bf16.
// ---------------------------------------------------------------------------
__device__ __forceinline__ unsigned short bf16_rne(float x)
{
    unsigned int b = __float_as_uint(x);
    b += 0x7FFFu + ((b >> 16) & 1u);
    return (unsigned short)(b >> 16);
}
__device__ __forceinline__ float bf16_tof(unsigned short h)
{
    return __uint_as_float(((unsigned int)h) << 16);
}

// ---------------------------------------------------------------------------
// MLP GEMM (fp32 vector; kept fp32 deliberately — q2 accuracy gates the
// topk-index ordering): C_partial[kc][64][N] = A[64][Kc] @ W[Kc][N]
// ---------------------------------------------------------------------------
__global__ __launch_bounds__(256) void gemm64_kernel(
    const float* __restrict__ A, const float* __restrict__ W,
    float* __restrict__ part, int K, int N, int kcK, int nBlocks)
{
    __shared__ float As[32][68];   // [k][m], padded
    __shared__ float Bs[32][68];   // [k][n], padded

    const int tid = threadIdx.x;
    const int nb = blockIdx.x % nBlocks;
    const int kc = blockIdx.x / nBlocks;
    const int kbeg = kc * kcK;

    const int tidm = tid >> 5;          // 0..7
    const int tidn = tid & 31;          // 0..31
    const int m0 = tidm * 8;
    const int n0g = nb * 64 + tidn * 2;

    float acc[8][2];
#pragma unroll
    for (int i = 0; i < 8; ++i) { acc[i][0] = 0.f; acc[i][1] = 0.f; }

    for (int k0 = kbeg; k0 < kbeg + kcK; k0 += 32) {
        __syncthreads();
#pragma unroll
        for (int i = 0; i < 2; ++i) {
            int q = tid + i * 256;                 // 0..511
            int row = q >> 3, c = q & 7;           // A tile: 64 rows x 32 k
            float4 va = *(const float4*)(A + (size_t)row * K + k0 + c * 4);
            As[c * 4 + 0][row] = va.x; As[c * 4 + 1][row] = va.y;
            As[c * 4 + 2][row] = va.z; As[c * 4 + 3][row] = va.w;
            int wr = q >> 4, wc = q & 15;          // W tile: 32 k x 64 n
            float4 vb = *(const float4*)(W + (size_t)(k0 + wr) * N + nb * 64 + wc * 4);
            *(float4*)&Bs[wr][wc * 4] = vb;
        }
        __syncthreads();
#pragma unroll
        for (int kk = 0; kk < 32; ++kk) {
            float4 a0 = *(const float4*)&As[kk][m0];
            float4 a1 = *(const float4*)&As[kk][m0 + 4];
            float2 b = *(const float2*)&Bs[kk][tidn * 2];
            float av[8] = {a0.x, a0.y, a0.z, a0.w, a1.x, a1.y, a1.z, a1.w};
#pragma unroll
            for (int i = 0; i < 8; ++i) {
                acc[i][0] += av[i] * b.x;
                acc[i][1] += av[i] * b.y;
            }
        }
    }
#pragma unroll
    for (int i = 0; i < 8; ++i) {
        float2 v; v.x = acc[i][0]; v.y = acc[i][1];
        *(float2*)(part + (size_t)(kc * B + m0 + i) * N + n0g) = v;
    }
}

// Reduce K-chunk partials + bias (+ optional exact GELU)
__global__ void mlp_reduce_kernel(const float* __restrict__ part,
                                  const float* __restrict__ bias,
                                  float* __restrict__ out, int N, int nchunks, int gelu)
{
    int e = blockIdx.x * 256 + threadIdx.x;   // over B*N
    int b = e / N, j = e - b * N;
    float s = bias[j];
    for (int c = 0; c < nchunks; ++c)
        s += part[(size_t)(c * B + b) * N + j];
    if (gelu)
        s = 0.5f * s * (1.0f + erff(s * 0.70710678118654752f));
    out[e] = s;
}

// q2 fp32 -> bf16 hi/lo split (4 elems/thread)
__global__ __launch_bounds__(256) void convert_q2_kernel(
    const float* __restrict__ q2,
    unsigned short* __restrict__ q2h, unsigned short* __restrict__ q2l)
{
    const int e = blockIdx.x * 256 + threadIdx.x;   // over B*D/4
    float4 v = ((const float4*)q2)[e];
    float xs[4] = {v.x, v.y, v.z, v.w};
    ushort4 hv, lv;
    unsigned short* ph = &hv.x;
    unsigned short* pl = &lv.x;
#pragma unroll
    for (int j = 0; j < 4; ++j) {
        unsigned short h = bf16_rne(xs[j]);
        ph[j] = h;
        pl[j] = bf16_rne(xs[j] - bf16_tof(h));
    }
    ((ushort4*)q2h)[e] = hv;
    ((ushort4*)q2l)[e] = lv;
}

// int64-layout hedge for vritti_types (values 0..4 -> high words all zero)
__device__ __forceinline__ bool types_is_i64(const int* t)
{
    int acc = 0;
#pragma unroll
    for (int j = 0; j < 16; ++j) acc |= t[2 * j + 1];
    return acc == 0;
}

// ---------------------------------------------------------------------------
// sims via split-bf16 MFMA, software-pipelined:
// logits = (q2 @ seed^T)*gate + vbias[type]
// grid = 782 (64-col tiles), 256 threads = 4 waves; wave w owns n-tile w.
// Pipeline: A (q2 hi/lo) double-buffered in LDS via register prefetch
// (regs loaded one step ahead -> ds_write never waits on vmcnt); B (seed)
// prefetched one step ahead into registers (read-once from HBM), split to
// bf16 hi/lo in-register. ONE barrier per K-step (ping-pong: write buf s&1,
// barrier, read buf s&1; next write targets the other buffer).
// ---------------------------------------------------------------------------
__global__ __launch_bounds__(256) void sims_mfma_kernel(
    const unsigned short* __restrict__ q2h, const unsigned short* __restrict__ q2l,
    const float* __restrict__ seed,
    const float* __restrict__ karma, const int* __restrict__ types,
    const float* __restrict__ vbias, float* __restrict__ logits)
{
    __shared__ __align__(16) unsigned short Ash[2][64][40];
    __shared__ __align__(16) unsigned short Asl[2][64][40];

    const int tid = threadIdx.x;
    const int n0 = blockIdx.x * 64;
    const int lane = tid & 63;
    const int wv  = tid >> 6;       // 0..3: n-tile of this wave
    const int l15 = lane & 15;
    const int lg  = lane >> 4;      // k-group 0..3

    const int srow = tid >> 2;      // A staging row 0..63
    const int sks  = tid & 3;       // A staging k-segment (8 elems)

    const int nrow = n0 + wv * 16 + l15;            // seed row this lane owns
    const bool nvalid = nrow < NSEED;
    const float* brow = seed + (size_t)nrow * D + 8 * lg;

    f32x4 acc[4];
#pragma unroll
    for (int t = 0; t < 4; ++t) acc[t] = (f32x4){0.f, 0.f, 0.f, 0.f};

    // prologue: step-0 A regs + B regs
    s16x8 rAh, rAl;
    {
        const size_t off = (size_t)srow * D + 8 * sks;
        rAh = *(const s16x8*)(q2h + off);
        rAl = *(const s16x8*)(q2l + off);
    }
    float4 bc0 = make_float4(0.f, 0.f, 0.f, 0.f), bc1 = bc0;
    if (nvalid) {
        bc0 = *(const float4*)(brow);
        bc1 = *(const float4*)(brow + 4);
    }

    const int NSTEP = D / 32;   // 64
    for (int s = 0; s < NSTEP; ++s) {
        const int cur = s & 1;
        // stage A(s) from regs (loaded a full step ago -> no vmcnt stall)
        *(s16x8*)&Ash[cur][srow][8 * sks] = rAh;
        *(s16x8*)&Asl[cur][srow][8 * sks] = rAl;
        // prefetch step s+1 (A regs + B regs) — lands during this step's MFMA
        float4 bn0 = make_float4(0.f, 0.f, 0.f, 0.f), bn1 = bn0;
        if (s + 1 < NSTEP) {
            const int k1 = (s + 1) * 32;
            const size_t off = (size_t)srow * D + k1 + 8 * sks;
            rAh = *(const s16x8*)(q2h + off);
            rAl = *(const s16x8*)(q2l + off);
            if (nvalid) {
                bn0 = *(const float4*)(brow + k1);
                bn1 = *(const float4*)(brow + k1 + 4);
            }
        }
        __syncthreads();
        // convert current B regs to hi/lo bf16
        s16x8 bh, bl;
        {
            float xs[8] = {bc0.x, bc0.y, bc0.z, bc0.w, bc1.x, bc1.y, bc1.z, bc1.w};
#pragma unroll
            for (int j = 0; j < 8; ++j) {
                unsigned short hu = bf16_rne(xs[j]);
                bh[j] = (short)hu;
                bl[j] = (short)bf16_rne(xs[j] - bf16_tof(hu));
            }
        }
#pragma unroll
        for (int t = 0; t < 4; ++t) {
            s16x8 ah = *(const s16x8*)&Ash[cur][t * 16 + l15][8 * lg];
            s16x8 al = *(const s16x8*)&Asl[cur][t * 16 + l15][8 * lg];
            acc[t] = __builtin_amdgcn_mfma_f32_16x16x32_bf16(ah, bh, acc[t], 0, 0, 0);
            acc[t] = __builtin_amdgcn_mfma_f32_16x16x32_bf16(al, bh, acc[t], 0, 0, 0);
            acc[t] = __builtin_amdgcn_mfma_f32_16x16x32_bf16(ah, bl, acc[t], 0, 0, 0);
        }
        bc0 = bn0; bc1 = bn1;
    }

    // epilogue: gate + vritti bias. D layout: col=lane&15, row=4*lg+reg.
    if (nvalid) {
        const bool i64 = types_is_i64(types);
        float ka = karma[nrow];
        float gate = 1.0f / (1.0f + expf(-(ka + 0.3f) * 10.0f));
        int ty = i64 ? types[2 * nrow] : types[nrow];
        float bias = vbias[ty];
#pragma unroll
        for (int t = 0; t < 4; ++t) {
#pragma unroll
            for (int r = 0; r < 4; ++r) {
                int m = t * 16 + lg * 4 + r;
                logits[(size_t)m * NSEED + nrow] = acc[t][r] * gate + bias;
            }
        }
    }
}

// ---------------------------------------------------------------------------
// Per-(row,chunk): online softmax partial (m,s) + chunk top-CEMIT.
// grid = 64 rows * 64 chunks, 64 threads (1 wave).
// ---------------------------------------------------------------------------
__global__ __launch_bounds__(64) void chunk_topk_kernel(
    const float* __restrict__ logits,
    float* __restrict__ chunk_m, float* __restrict__ chunk_s,
    float* __restrict__ cand_val, int* __restrict__ cand_idx)
{
    const int bid = blockIdx.x;
    const int row = bid >> 6, chunk = bid & 63;
    const int start = chunk * CHUNK_SZ;
    const int end = min(start + CHUNK_SZ, NSEED);
    const int lane = threadIdx.x;
    const float* Lrow = logits + (size_t)row * NSEED;

    float v[13];
#pragma unroll
    for (int j = 0; j < 13; ++j) {
        int e = start + lane + j * 64;
        v[j] = (e < end) ? Lrow[e] : -INFINITY;
    }

    // online (m, s) partial: s = sum exp(2*(l - m))
    float m = v[0];
#pragma unroll
    for (int j = 1; j < 13; ++j) m = fmaxf(m, v[j]);
    float s = 0.f;
#pragma unroll
    for (int j = 0; j < 13; ++j) s += expf(2.f * (v[j] - m));
#pragma unroll
    for (int d = 1; d < 64; d <<= 1) {
        float mo = __shfl_xor(m, d);
        float so = __shfl_xor(s, d);
        float nm = fmaxf(m, mo);
        s = s * expf(2.f * (m - nm)) + so * expf(2.f * (mo - nm));
        m = nm;
    }
    if (lane == 0) { chunk_m[bid] = m; chunk_s[bid] = s; }

    // chunk top-CEMIT via wave-argmax iterations (lower index wins ties)
    for (int it = 0; it < CEMIT; ++it) {
        float bv = v[0]; int bj = 0;
#pragma unroll
        for (int j = 1; j < 13; ++j)
            if (v[j] > bv) { bv = v[j]; bj = j; }
        int bi = start + lane + bj * 64;
#pragma unroll
        for (int d = 1; d < 64; d <<= 1) {
            float ov = __shfl_xor(bv, d);
            int oi = __shfl_xor(bi, d);
            if (ov > bv || (ov == bv && oi < bi)) { bv = ov; bi = oi; }
        }
        if (lane == 0) {
            cand_val[bid * CEMIT + it] = bv;
            cand_idx[bid * CEMIT + it] = bi;
        }
#pragma unroll
        for (int j = 0; j < 13; ++j)
            if (start + lane + j * 64 == bi) v[j] = -INFINITY;
    }
}

// ---------------------------------------------------------------------------
// Per-row merge: 64 (m,s) partials -> (M, 1/S); 4096 candidates -> top-NCAND
// candidate indices (by MFMA logit; candidate set, not final order).
// ---------------------------------------------------------------------------
__global__ __launch_bounds__(256) void merge_topk_kernel(
    const float* __restrict__ chunk_m, const float* __restrict__ chunk_s,
    const float* __restrict__ cand_val, const int* __restrict__ cand_idx,
    float* __restrict__ row_M, float* __restrict__ row_rS,
    int* __restrict__ cand2)
{
    const int row = blockIdx.x;
    const int tid = threadIdx.x;
    const int lane = tid & 63, wave = tid >> 6;
    __shared__ float rv[4];
    __shared__ int ri[4];

    if (wave == 0) {
        float m = chunk_m[row * 64 + lane];
        float s = chunk_s[row * 64 + lane];
#pragma unroll
        for (int d = 1; d < 64; d <<= 1) {
            float mo = __shfl_xor(m, d);
            float so = __shfl_xor(s, d);
            float nm = fmaxf(m, mo);
            s = s * expf(2.f * (m - nm)) + so * expf(2.f * (mo - nm));
            m = nm;
        }
        if (lane == 0) { row_M[row] = m; row_rS[row] = 1.0f / s; }
    }

    float v[16]; int ix[16];
#pragma unroll
    for (int j = 0; j < 16; ++j) {
        int e = tid + j * 256;                      // 4096 = NCHUNKS*CEMIT
        v[j] = cand_val[row * (NCHUNKS * CEMIT) + e];
        ix[j] = cand_idx[row * (NCHUNKS * CEMIT) + e];
    }

    for (int it = 0; it < NCAND; ++it) {
        float bv = v[0]; int bi = ix[0];
#pragma unroll
        for (int j = 1; j < 16; ++j)
            if (v[j] > bv || (v[j] == bv && ix[j] < bi)) { bv = v[j]; bi = ix[j]; }
#pragma unroll
        for (int d = 1; d < 64; d <<= 1) {
            float ov = __shfl_xor(bv, d);
            int oi = __shfl_xor(bi, d);
            if (ov > bv || (ov == bv && oi < bi)) { bv = ov; bi = oi; }
        }
        if (lane == 0) { rv[wave] = bv; ri[wave] = bi; }
        __syncthreads();
        float wv = rv[0]; int wi = ri[0];
#pragma unroll
        for (int w = 1; w < 4; ++w)
            if (rv[w] > wv || (rv[w] == wv && ri[w] < wi)) { wv = rv[w]; wi = ri[w]; }
        __syncthreads();
        if (tid == 0) cand2[row * NCAND + it] = wi;
#pragma unroll
        for (int j = 0; j < 16; ++j)
            if (ix[j] == wi) v[j] = -INFINITY;
    }
}

// ---------------------------------------------------------------------------
// Exact rescore of candidates: fp64 dot(q2[row], seed[idx]) + fp32 gate/bias.
// grid = (NCAND/4, 64 rows), 256 threads = 4 waves (one candidate per wave).
// ---------------------------------------------------------------------------
__global__ __launch_bounds__(256) void rescore_kernel(
    const float* __restrict__ q2, const float* __restrict__ seed,
    const float* __restrict__ karma, const int* __restrict__ types,
    const float* __restrict__ vbias, const int* __restrict__ cand2,
    float* __restrict__ rvals)
{
    const int row = blockIdx.y;
    const int wv = threadIdx.x >> 6, lane = threadIdx.x & 63;
    const int ci = blockIdx.x * 4 + wv;             // 0..NCAND-1
    const int idx = cand2[row * NCAND + ci];
    const float* qrow = q2 + (size_t)row * D;
    const float* srow = seed + (size_t)idx * D;

    double s = 0.0;
#pragma unroll
    for (int i = 0; i < 8; ++i) {
        float4 a = *(const float4*)(qrow + lane * 4 + i * 256);
        float4 b = *(const float4*)(srow + lane * 4 + i * 256);
        s += (double)a.x * (double)b.x + (double)a.y * (double)b.y
           + (double)a.z * (double)b.z + (double)a.w * (double)b.w;
    }
#pragma unroll
    for (int d = 1; d < 64; d <<= 1) s += __shfl_xor(s, d);

    if (lane == 0) {
        float ka = karma[idx];
        float gate = 1.0f / (1.0f + expf(-(ka + 0.3f) * 10.0f));
        bool i64 = types_is_i64(types);
        int ty = i64 ? types[2 * idx] : types[idx];
        rvals[row * NCAND + ci] = (float)s * gate + vbias[ty];
    }
}

// ---------------------------------------------------------------------------
// Final per-row top-50 (sorted desc, lower index on ties) from NCAND rescored.
// grid = 64, 64 threads (1 wave, one candidate per lane).
// ---------------------------------------------------------------------------
__global__ __launch_bounds__(64) void final50_kernel(
    const float* __restrict__ rvals, const int* __restrict__ cand2,
    float* __restrict__ out_idx_f, int* __restrict__ topk_idx)
{
    const int row = blockIdx.x;
    const int lane = threadIdx.x;

    float v = rvals[row * NCAND + lane];
    int ix = cand2[row * NCAND + lane];

    for (int it = 0; it < KTOP; ++it) {
        float bv = v; int bi = ix;
#pragma unroll
        for (int d = 1; d < 64; d <<= 1) {
            float ov = __shfl_xor(bv, d);
            int oi = __shfl_xor(bi, d);
            if (ov > bv || (ov == bv && oi < bi)) { bv = ov; bi = oi; }
        }
        if (lane == 0) {
            out_idx_f[row * KTOP + it] = (float)bi;
            topk_idx[row * KTOP + it] = bi;
        }
        if (ix == bi) v = -INFINITY;
    }
}

// attention weights: w = exp(2*(l - M)) / S
__global__ void weights_kernel(const float* __restrict__ logits,
                               const float* __restrict__ row_M,
                               const float* __restrict__ row_rS,
                               float* __restrict__ attn)
{
    const int row = blockIdx.y;
    const int f = blockIdx.x * 256 + threadIdx.x;
    if (f >= NSEED / 4) return;
    const float M = row_M[row], rS = row_rS[row];
    float4 l = ((const float4*)(logits + (size_t)row * NSEED))[f];
    float4 w;
    w.x = expf(2.f * (l.x - M)) * rS;
    w.y = expf(2.f * (l.y - M)) * rS;
    w.z = expf(2.f * (l.z - M)) * rS;
    w.w = expf(2.f * (l.w - M)) * rS;
    ((float4*)(attn + (size_t)row * NSEED))[f] = w;
}

// chitta gather: 2048 floats per (row,k)
__global__ void gather_kernel(const float* __restrict__ seed,
                              const int* __restrict__ topk_idx,
                              float* __restrict__ chitta)
{
    const int k = blockIdx.x, row = blockIdx.y;
    const int idx = topk_idx[row * KTOP + k];
    const float4* src = (const float4*)(seed + (size_t)idx * D);
    float4* dst = (float4*)(chitta + (size_t)(row * KTOP + k) * D);
#pragma unroll
    for (int j = 0; j < 2; ++j)
        dst[threadIdx.x + j * 256] = src[threadIdx.x + j * 256];
}

extern "C" void kernel_launch(void* const* d_in, const int* in_sizes, int n_in,
                              void* d_out, int out_size, void* d_ws, size_t ws_size,
                              hipStream_t stream)
{
    const float* query = (const float*)d_in[0];
    const int*   types = (const int*)d_in[1];
    const float* seed  = (const float*)d_in[2];
    const float* karma = (const float*)d_in[3];
    const float* vbias = (const float*)d_in[4];
    const float* W1    = (const float*)d_in[5];
    const float* b1    = (const float*)d_in[6];
    const float* W2    = (const float*)d_in[7];
    const float* b2    = (const float*)d_in[8];

    float* ws = (float*)d_ws;
    float* logits = ws + WS_LOGITS;
    float* h      = ws + WS_H;
    float* q2     = ws + WS_Q2;
    float* part   = ws + WS_PART;
    float* cval   = ws + WS_CVAL;
    int*   cidx   = (int*)(ws + WS_CIDX);
    float* cm     = ws + WS_CM;
    float* cs     = ws + WS_CS;
    float* rM     = ws + WS_RM;
    float* rS     = ws + WS_RS;

    // sub-allocations inside PART (free after mlp_reduce layer 2):
    unsigned short* q2h = (unsigned short*)(part + WSP_Q2H);  // 64*2048 ushorts
    unsigned short* q2l = q2h + (size_t)B * D;
    int*   cand2 = (int*)(part + WSP_CAND);                   // 64*64
    float* rvals = part + WSP_RVAL;                           // 64*64
    int*   tidx  = (int*)(part + WSP_TIDX);                   // 64*50

    float* outv   = (float*)d_out;
    float* chitta = outv;                                   // [64][50][2048]
    float* attn   = outv + (size_t)B * KTOP * D;            // [64][50000]
    float* oidxf  = attn + (size_t)B * NSEED;               // [64][50] as float

    // MLP layer 1: 64 n-blocks x 4 k-chunks (K chunk = 512)
    gemm64_kernel<<<256, 256, 0, stream>>>(query, W1, part, D, H, 512, H / 64);
    mlp_reduce_kernel<<<(B * H) / 256, 256, 0, stream>>>(part, b1, h, H, 4, 1);
    // MLP layer 2: 32 n-blocks x 8 k-chunks (K chunk = 512)
    gemm64_kernel<<<256, 256, 0, stream>>>(h, W2, part, H, D, 512, D / 64);
    mlp_reduce_kernel<<<(B * D) / 256, 256, 0, stream>>>(part, b2, q2, D, 8, 0);
    // split q2 into bf16 hi/lo
    convert_q2_kernel<<<(B * D / 4) / 256, 256, 0, stream>>>(q2, q2h, q2l);
    // similarity + gate + bias -> logits (pipelined split-bf16 MFMA)
    sims_mfma_kernel<<<(NSEED + 63) / 64, 256, 0, stream>>>(q2h, q2l, seed, karma, types, vbias, logits);
    // per-chunk stats + top-64 candidates
    chunk_topk_kernel<<<B * NCHUNKS, 64, 0, stream>>>(logits, cm, cs, cval, cidx);
    // per-row merge -> (M, 1/S) + top-NCAND candidate set
    merge_topk_kernel<<<B, 256, 0, stream>>>(cm, cs, cval, cidx, rM, rS, cand2);
    // exact fp64 rescore of candidates
    rescore_kernel<<<dim3(NCAND / 4, B), 256, 0, stream>>>(q2, seed, karma, types, vbias, cand2, rvals);
    // final sorted top-50 indices
    final50_kernel<<<B, 64, 0, stream>>>(rvals, cand2, oidxf, tidx);
    // full attention weights
    weights_kernel<<<dim3((NSEED / 4 + 255) / 256, B), 256, 0, stream>>>(logits, rM, rS, attn);
    // retrieved embeddings
    gather_kernel<<<dim3(KTOP, B), 256, 0, stream>>>(seed, tidx, chitta);
}

// Round 6
// 339.864 us; speedup vs baseline: 1.9409x; 1.3123x over previous
//
#include <hip/hip_runtime.h>
#include <math.h>

// Problem constants
#define B 64
#define D 2048
#define H 4096
#define NSEED 50000
#define KTOP 50
#define NCAND 64            // rescored candidates per row
#define CEMIT 20            // candidates emitted per chunk (coverage: P(chunk holds >20 of top-64) ~ 2e-20)
#define NCHUNKS 64          // topk chunks per row
#define CHUNK_SZ 782        // ceil(50000/64)

// ws layout (float offsets)
#define WS_LOGITS   0                         // 64*50000 = 3,200,000
#define WS_H        3200000                   // 64*4096  = 262,144
#define WS_Q2       (WS_H + B*H)              // 64*2048  = 131,072
#define WS_PART     (WS_Q2 + B*D)             // 1,048,576 (MLP partials; later cand/rvals)
#define WS_CVAL     (WS_PART + 1048576)       // 64*64*20 = 81,920 (region sized 262,144)
#define WS_CIDX     (WS_CVAL + 262144)        // ints
#define WS_CM       (WS_CIDX + 262144)        // 4096
#define WS_CS       (WS_CM + 4096)            // 4096
#define WS_RM       (WS_CS + 4096)            // 64
#define WS_RS       (WS_RM + 64)              // 64
#define WS_Q2HL     (WS_RS + 64)              // q2h+q2l: 2*131072 ushorts = 131,072 floats
// sub-allocations inside the (sequentially freed) PART region:
#define WSP_CAND    200000                    // 64*64 ints
#define WSP_RVAL    220000                    // 64*64 floats
#define WSP_TIDX    240000                    // 64*50 ints

typedef short s16x8 __attribute__((ext_vector_type(8)));
typedef float f32x4 __attribute__((ext_vector_type(4)));

// ---------------------------------------------------------------------------
// bf16 split helpers: x ~= hi + lo, both RNE bf16.
// ---------------------------------------------------------------------------
__device__ __forceinline__ unsigned short bf16_rne(float x)
{
    unsigned int b = __float_as_uint(x);
    b += 0x7FFFu + ((b >> 16) & 1u);
    return (unsigned short)(b >> 16);
}
__device__ __forceinline__ float bf16_tof(unsigned short h)
{
    return __uint_as_float(((unsigned int)h) << 16);
}

// ---------------------------------------------------------------------------
// MLP GEMM (fp32 vector; kept fp32 deliberately — q2 accuracy gates the
// topk-index ordering): C_partial[kc][64][N] = A[64][Kc] @ W[Kc][N]
// ---------------------------------------------------------------------------
__global__ __launch_bounds__(256) void gemm64_kernel(
    const float* __restrict__ A, const float* __restrict__ W,
    float* __restrict__ part, int K, int N, int kcK, int nBlocks)
{
    __shared__ float As[32][68];   // [k][m], padded
    __shared__ float Bs[32][68];   // [k][n], padded

    const int tid = threadIdx.x;
    const int nb = blockIdx.x % nBlocks;
    const int kc = blockIdx.x / nBlocks;
    const int kbeg = kc * kcK;

    const int tidm = tid >> 5;          // 0..7
    const int tidn = tid & 31;          // 0..31
    const int m0 = tidm * 8;
    const int n0g = nb * 64 + tidn * 2;

    float acc[8][2];
#pragma unroll
    for (int i = 0; i < 8; ++i) { acc[i][0] = 0.f; acc[i][1] = 0.f; }

    for (int k0 = kbeg; k0 < kbeg + kcK; k0 += 32) {
        __syncthreads();
#pragma unroll
        for (int i = 0; i < 2; ++i) {
            int q = tid + i * 256;                 // 0..511
            int row = q >> 3, c = q & 7;           // A tile: 64 rows x 32 k
            float4 va = *(const float4*)(A + (size_t)row * K + k0 + c * 4);
            As[c * 4 + 0][row] = va.x; As[c * 4 + 1][row] = va.y;
            As[c * 4 + 2][row] = va.z; As[c * 4 + 3][row] = va.w;
            int wr = q >> 4, wc = q & 15;          // W tile: 32 k x 64 n
            float4 vb = *(const float4*)(W + (size_t)(k0 + wr) * N + nb * 64 + wc * 4);
            *(float4*)&Bs[wr][wc * 4] = vb;
        }
        __syncthreads();
#pragma unroll
        for (int kk = 0; kk < 32; ++kk) {
            float4 a0 = *(const float4*)&As[kk][m0];
            float4 a1 = *(const float4*)&As[kk][m0 + 4];
            float2 b = *(const float2*)&Bs[kk][tidn * 2];
            float av[8] = {a0.x, a0.y, a0.z, a0.w, a1.x, a1.y, a1.z, a1.w};
#pragma unroll
            for (int i = 0; i < 8; ++i) {
                acc[i][0] += av[i] * b.x;
                acc[i][1] += av[i] * b.y;
            }
        }
    }
#pragma unroll
    for (int i = 0; i < 8; ++i) {
        float2 v; v.x = acc[i][0]; v.y = acc[i][1];
        *(float2*)(part + (size_t)(kc * B + m0 + i) * N + n0g) = v;
    }
}

// Reduce K-chunk partials + bias (+ optional exact GELU).
// When uh/ul are non-null (layer 2), also emits the bf16 hi/lo split of out.
__global__ void mlp_reduce_kernel(const float* __restrict__ part,
                                  const float* __restrict__ bias,
                                  float* __restrict__ out, int N, int nchunks, int gelu,
                                  unsigned short* __restrict__ uh,
                                  unsigned short* __restrict__ ul)
{
    int e = blockIdx.x * 256 + threadIdx.x;   // over B*N
    int b = e / N, j = e - b * N;
    float s = bias[j];
    for (int c = 0; c < nchunks; ++c)
        s += part[(size_t)(c * B + b) * N + j];
    if (gelu)
        s = 0.5f * s * (1.0f + erff(s * 0.70710678118654752f));
    out[e] = s;
    if (uh) {
        unsigned short h = bf16_rne(s);
        uh[e] = h;
        ul[e] = bf16_rne(s - bf16_tof(h));
    }
}

// int64-layout hedge for vritti_types (values 0..4 -> high words all zero)
__device__ __forceinline__ bool types_is_i64(const int* t)
{
    int acc = 0;
#pragma unroll
    for (int j = 0; j < 16; ++j) acc |= t[2 * j + 1];
    return acc == 0;
}

// ---------------------------------------------------------------------------
// sims via split-bf16 MFMA, K-step 64, depth-2 register pipeline:
// logits = (q2 @ seed^T)*gate + vbias[type]
// grid = 782 (64-col tiles), 256 threads = 4 waves; wave w owns n-tile w.
// Per phase (one 64-K tile): stage A (q2 hi/lo) into ping-pong LDS from regs
// loaded TWO phases earlier; issue loads for phase+2; one barrier; 2x
// {convert B regs (loaded two phases ago) -> bf16 hi/lo; 12 MFMA}.
// 32 barriers total; ~800+ cyc issue-to-use distance on every global load.
// ---------------------------------------------------------------------------
__global__ __launch_bounds__(256) void sims_mfma_kernel(
    const unsigned short* __restrict__ q2h, const unsigned short* __restrict__ q2l,
    const float* __restrict__ seed,
    const float* __restrict__ karma, const int* __restrict__ types,
    const float* __restrict__ vbias, float* __restrict__ logits)
{
    __shared__ __align__(16) unsigned short Ash[2][64][72];
    __shared__ __align__(16) unsigned short Asl[2][64][72];

    const int tid = threadIdx.x;
    const int n0 = blockIdx.x * 64;
    const int lane = tid & 63;
    const int wv  = tid >> 6;       // 0..3: n-tile of this wave
    const int l15 = lane & 15;
    const int lg  = lane >> 4;      // k-group 0..3

    const int srow = tid >> 2;      // A staging row 0..63
    const int seg  = tid & 3;       // A staging 16-short segment

    const int nrow = n0 + wv * 16 + l15;            // seed row this lane owns
    const bool nvalid = nrow < NSEED;
    const float* brow = seed + (size_t)nrow * D + 8 * lg;
    const size_t aoff = (size_t)srow * D + 16 * seg;

    f32x4 acc[4];
#pragma unroll
    for (int t = 0; t < 4; ++t) acc[t] = (f32x4){0.f, 0.f, 0.f, 0.f};

    // -------- pipeline registers (2 sets, static names) --------
    s16x8 a0ha, a0hb, a0la, a0lb;   // set 0 (even phases)
    s16x8 a1ha, a1hb, a1la, a1lb;   // set 1 (odd phases)
    float4 b00, b01, b02, b03;      // set 0 B: k +[0,4,32,36]
    float4 b10, b11, b12, b13;      // set 1 B

    // prologue: set0 <- phase 0 (kb=0), set1 <- phase 1 (kb=64)
    a0ha = *(const s16x8*)(q2h + aoff);
    a0hb = *(const s16x8*)(q2h + aoff + 8);
    a0la = *(const s16x8*)(q2l + aoff);
    a0lb = *(const s16x8*)(q2l + aoff + 8);
    a1ha = *(const s16x8*)(q2h + aoff + 64);
    a1hb = *(const s16x8*)(q2h + aoff + 72);
    a1la = *(const s16x8*)(q2l + aoff + 64);
    a1lb = *(const s16x8*)(q2l + aoff + 72);
    b00 = b01 = b02 = b03 = make_float4(0.f, 0.f, 0.f, 0.f);
    b10 = b11 = b12 = b13 = make_float4(0.f, 0.f, 0.f, 0.f);
    if (nvalid) {
        b00 = *(const float4*)(brow);      b01 = *(const float4*)(brow + 4);
        b02 = *(const float4*)(brow + 32); b03 = *(const float4*)(brow + 36);
        b10 = *(const float4*)(brow + 64); b11 = *(const float4*)(brow + 68);
        b12 = *(const float4*)(brow + 96); b13 = *(const float4*)(brow + 100);
    }

#define SIMS_CONV(F0, F1, BH, BL)                                          \
    {                                                                      \
        float xs[8] = {F0.x, F0.y, F0.z, F0.w, F1.x, F1.y, F1.z, F1.w};    \
        _Pragma("unroll")                                                  \
        for (int j = 0; j < 8; ++j) {                                      \
            unsigned short hu = bf16_rne(xs[j]);                           \
            BH[j] = (short)hu;                                             \
            BL[j] = (short)bf16_rne(xs[j] - bf16_tof(hu));                 \
        }                                                                  \
    }

#define SIMS_MFMA(BUF, KS, BH, BL)                                         \
    _Pragma("unroll")                                                      \
    for (int t = 0; t < 4; ++t) {                                          \
        s16x8 ah = *(const s16x8*)&Ash[BUF][t * 16 + l15][KS * 32 + 8 * lg]; \
        s16x8 al = *(const s16x8*)&Asl[BUF][t * 16 + l15][KS * 32 + 8 * lg]; \
        acc[t] = __builtin_amdgcn_mfma_f32_16x16x32_bf16(ah, BH, acc[t], 0, 0, 0); \
        acc[t] = __builtin_amdgcn_mfma_f32_16x16x32_bf16(al, BH, acc[t], 0, 0, 0); \
        acc[t] = __builtin_amdgcn_mfma_f32_16x16x32_bf16(ah, BL, acc[t], 0, 0, 0); \
    }

    for (int u = 0; u < 16; ++u) {
        // ================= phase 0: buffer 0, set 0 =================
        *(s16x8*)&Ash[0][srow][16 * seg]     = a0ha;
        *(s16x8*)&Ash[0][srow][16 * seg + 8] = a0hb;
        *(s16x8*)&Asl[0][srow][16 * seg]     = a0la;
        *(s16x8*)&Asl[0][srow][16 * seg + 8] = a0lb;
        float4 n0a = make_float4(0.f, 0.f, 0.f, 0.f), n0b = n0a, n0c = n0a, n0d = n0a;
        if (u < 15) {
            const int kb = 128 * u + 128;          // phase 2u+2
            a0ha = *(const s16x8*)(q2h + aoff + kb);
            a0hb = *(const s16x8*)(q2h + aoff + kb + 8);
            a0la = *(const s16x8*)(q2l + aoff + kb);
            a0lb = *(const s16x8*)(q2l + aoff + kb + 8);
            if (nvalid) {
                n0a = *(const float4*)(brow + kb);      n0b = *(const float4*)(brow + kb + 4);
                n0c = *(const float4*)(brow + kb + 32); n0d = *(const float4*)(brow + kb + 36);
            }
        }
        __syncthreads();
        {
            s16x8 bh, bl;
            SIMS_CONV(b00, b01, bh, bl);
            SIMS_MFMA(0, 0, bh, bl);
            SIMS_CONV(b02, b03, bh, bl);
            SIMS_MFMA(0, 1, bh, bl);
        }
        b00 = n0a; b01 = n0b; b02 = n0c; b03 = n0d;

        // ================= phase 1: buffer 1, set 1 =================
        *(s16x8*)&Ash[1][srow][16 * seg]     = a1ha;
        *(s16x8*)&Ash[1][srow][16 * seg + 8] = a1hb;
        *(s16x8*)&Asl[1][srow][16 * seg]     = a1la;
        *(s16x8*)&Asl[1][srow][16 * seg + 8] = a1lb;
        float4 n1a = make_float4(0.f, 0.f, 0.f, 0.f), n1b = n1a, n1c = n1a, n1d = n1a;
        if (u < 15) {
            const int kb = 128 * u + 192;          // phase 2u+3
            a1ha = *(const s16x8*)(q2h + aoff + kb);
            a1hb = *(const s16x8*)(q2h + aoff + kb + 8);
            a1la = *(const s16x8*)(q2l + aoff + kb);
            a1lb = *(const s16x8*)(q2l + aoff + kb + 8);
            if (nvalid) {
                n1a = *(const float4*)(brow + kb);      n1b = *(const float4*)(brow + kb + 4);
                n1c = *(const float4*)(brow + kb + 32); n1d = *(const float4*)(brow + kb + 36);
            }
        }
        __syncthreads();
        {
            s16x8 bh, bl;
            SIMS_CONV(b10, b11, bh, bl);
            SIMS_MFMA(1, 0, bh, bl);
            SIMS_CONV(b12, b13, bh, bl);
            SIMS_MFMA(1, 1, bh, bl);
        }
        b10 = n1a; b11 = n1b; b12 = n1c; b13 = n1d;
    }
#undef SIMS_CONV
#undef SIMS_MFMA

    // epilogue: gate + vritti bias. D layout: col=lane&15, row=4*lg+reg.
    if (nvalid) {
        const bool i64 = types_is_i64(types);
        float ka = karma[nrow];
        float gate = 1.0f / (1.0f + expf(-(ka + 0.3f) * 10.0f));
        int ty = i64 ? types[2 * nrow] : types[nrow];
        float bias = vbias[ty];
#pragma unroll
        for (int t = 0; t < 4; ++t) {
#pragma unroll
            for (int r = 0; r < 4; ++r) {
                int m = t * 16 + lg * 4 + r;
                logits[(size_t)m * NSEED + nrow] = acc[t][r] * gate + bias;
            }
        }
    }
}

// ---------------------------------------------------------------------------
// Per-(row,chunk): online softmax partial (m,s) + chunk top-CEMIT.
// grid = 64 rows * 64 chunks, 64 threads (1 wave).
// ---------------------------------------------------------------------------
__global__ __launch_bounds__(64) void chunk_topk_kernel(
    const float* __restrict__ logits,
    float* __restrict__ chunk_m, float* __restrict__ chunk_s,
    float* __restrict__ cand_val, int* __restrict__ cand_idx)
{
    const int bid = blockIdx.x;
    const int row = bid >> 6, chunk = bid & 63;
    const int start = chunk * CHUNK_SZ;
    const int end = min(start + CHUNK_SZ, NSEED);
    const int lane = threadIdx.x;
    const float* Lrow = logits + (size_t)row * NSEED;

    float v[13];
#pragma unroll
    for (int j = 0; j < 13; ++j) {
        int e = start + lane + j * 64;
        v[j] = (e < end) ? Lrow[e] : -INFINITY;
    }

    // online (m, s) partial: s = sum exp(2*(l - m))
    float m = v[0];
#pragma unroll
    for (int j = 1; j < 13; ++j) m = fmaxf(m, v[j]);
    float s = 0.f;
#pragma unroll
    for (int j = 0; j < 13; ++j) s += expf(2.f * (v[j] - m));
#pragma unroll
    for (int d = 1; d < 64; d <<= 1) {
        float mo = __shfl_xor(m, d);
        float so = __shfl_xor(s, d);
        float nm = fmaxf(m, mo);
        s = s * expf(2.f * (m - nm)) + so * expf(2.f * (mo - nm));
        m = nm;
    }
    if (lane == 0) { chunk_m[bid] = m; chunk_s[bid] = s; }

    // chunk top-CEMIT via wave-argmax iterations (lower index wins ties)
    for (int it = 0; it < CEMIT; ++it) {
        float bv = v[0]; int bj = 0;
#pragma unroll
        for (int j = 1; j < 13; ++j)
            if (v[j] > bv) { bv = v[j]; bj = j; }
        int bi = start + lane + bj * 64;
#pragma unroll
        for (int d = 1; d < 64; d <<= 1) {
            float ov = __shfl_xor(bv, d);
            int oi = __shfl_xor(bi, d);
            if (ov > bv || (ov == bv && oi < bi)) { bv = ov; bi = oi; }
        }
        if (lane == 0) {
            cand_val[bid * CEMIT + it] = bv;
            cand_idx[bid * CEMIT + it] = bi;
        }
#pragma unroll
        for (int j = 0; j < 13; ++j)
            if (start + lane + j * 64 == bi) v[j] = -INFINITY;
    }
}

// ---------------------------------------------------------------------------
// Per-row merge: 64 (m,s) partials -> (M, 1/S); 1280 candidates -> top-NCAND
// candidate indices (by MFMA logit; candidate set, not final order).
// ---------------------------------------------------------------------------
__global__ __launch_bounds__(256) void merge_topk_kernel(
    const float* __restrict__ chunk_m, const float* __restrict__ chunk_s,
    const float* __restrict__ cand_val, const int* __restrict__ cand_idx,
    float* __restrict__ row_M, float* __restrict__ row_rS,
    int* __restrict__ cand2)
{
    const int row = blockIdx.x;
    const int tid = threadIdx.x;
    const int lane = tid & 63, wave = tid >> 6;
    __shared__ float rv[4];
    __shared__ int ri[4];

    if (wave == 0) {
        float m = chunk_m[row * 64 + lane];
        float s = chunk_s[row * 64 + lane];
#pragma unroll
        for (int d = 1; d < 64; d <<= 1) {
            float mo = __shfl_xor(m, d);
            float so = __shfl_xor(s, d);
            float nm = fmaxf(m, mo);
            s = s * expf(2.f * (m - nm)) + so * expf(2.f * (mo - nm));
            m = nm;
        }
        if (lane == 0) { row_M[row] = m; row_rS[row] = 1.0f / s; }
    }

    float v[5]; int ix[5];
#pragma unroll
    for (int j = 0; j < 5; ++j) {
        int e = tid + j * 256;                      // 1280 = NCHUNKS*CEMIT
        v[j] = cand_val[row * (NCHUNKS * CEMIT) + e];
        ix[j] = cand_idx[row * (NCHUNKS * CEMIT) + e];
    }

    for (int it = 0; it < NCAND; ++it) {
        float bv = v[0]; int bi = ix[0];
#pragma unroll
        for (int j = 1; j < 5; ++j)
            if (v[j] > bv || (v[j] == bv && ix[j] < bi)) { bv = v[j]; bi = ix[j]; }
#pragma unroll
        for (int d = 1; d < 64; d <<= 1) {
            float ov = __shfl_xor(bv, d);
            int oi = __shfl_xor(bi, d);
            if (ov > bv || (ov == bv && oi < bi)) { bv = ov; bi = oi; }
        }
        if (lane == 0) { rv[wave] = bv; ri[wave] = bi; }
        __syncthreads();
        float wv = rv[0]; int wi = ri[0];
#pragma unroll
        for (int w = 1; w < 4; ++w)
            if (rv[w] > wv || (rv[w] == wv && ri[w] < wi)) { wv = rv[w]; wi = ri[w]; }
        __syncthreads();
        if (tid == 0) cand2[row * NCAND + it] = wi;
#pragma unroll
        for (int j = 0; j < 5; ++j)
            if (ix[j] == wi) v[j] = -INFINITY;
    }
}

// ---------------------------------------------------------------------------
// Exact rescore of candidates: fp64 dot(q2[row], seed[idx]) + fp32 gate/bias.
// grid = (NCAND/4, 64 rows), 256 threads = 4 waves (one candidate per wave).
// ---------------------------------------------------------------------------
__global__ __launch_bounds__(256) void rescore_kernel(
    const float* __restrict__ q2, const float* __restrict__ seed,
    const float* __restrict__ karma, const int* __restrict__ types,
    const float* __restrict__ vbias, const int* __restrict__ cand2,
    float* __restrict__ rvals)
{
    const int row = blockIdx.y;
    const int wv = threadIdx.x >> 6, lane = threadIdx.x & 63;
    const int ci = blockIdx.x * 4 + wv;             // 0..NCAND-1
    const int idx = cand2[row * NCAND + ci];
    const float* qrow = q2 + (size_t)row * D;
    const float* srow = seed + (size_t)idx * D;

    double s = 0.0;
#pragma unroll
    for (int i = 0; i < 8; ++i) {
        float4 a = *(const float4*)(qrow + lane * 4 + i * 256);
        float4 b = *(const float4*)(srow + lane * 4 + i * 256);
        s += (double)a.x * (double)b.x + (double)a.y * (double)b.y
           + (double)a.z * (double)b.z + (double)a.w * (double)b.w;
    }
#pragma unroll
    for (int d = 1; d < 64; d <<= 1) s += __shfl_xor(s, d);

    if (lane == 0) {
        float ka = karma[idx];
        float gate = 1.0f / (1.0f + expf(-(ka + 0.3f) * 10.0f));
        bool i64 = types_is_i64(types);
        int ty = i64 ? types[2 * idx] : types[idx];
        rvals[row * NCAND + ci] = (float)s * gate + vbias[ty];
    }
}

// ---------------------------------------------------------------------------
// Final per-row top-50 (sorted desc, lower index on ties) from NCAND rescored.
// grid = 64, 64 threads (1 wave, one candidate per lane).
// ---------------------------------------------------------------------------
__global__ __launch_bounds__(64) void final50_kernel(
    const float* __restrict__ rvals, const int* __restrict__ cand2,
    float* __restrict__ out_idx_f, int* __restrict__ topk_idx)
{
    const int row = blockIdx.x;
    const int lane = threadIdx.x;

    float v = rvals[row * NCAND + lane];
    int ix = cand2[row * NCAND + lane];

    for (int it = 0; it < KTOP; ++it) {
        float bv = v; int bi = ix;
#pragma unroll
        for (int d = 1; d < 64; d <<= 1) {
            float ov = __shfl_xor(bv, d);
            int oi = __shfl_xor(bi, d);
            if (ov > bv || (ov == bv && oi < bi)) { bv = ov; bi = oi; }
        }
        if (lane == 0) {
            out_idx_f[row * KTOP + it] = (float)bi;
            topk_idx[row * KTOP + it] = bi;
        }
        if (ix == bi) v = -INFINITY;
    }
}

// attention weights: w = exp(2*(l - M)) / S
__global__ void weights_kernel(const float* __restrict__ logits,
                               const float* __restrict__ row_M,
                               const float* __restrict__ row_rS,
                               float* __restrict__ attn)
{
    const int row = blockIdx.y;
    const int f = blockIdx.x * 256 + threadIdx.x;
    if (f >= NSEED / 4) return;
    const float M = row_M[row], rS = row_rS[row];
    float4 l = ((const float4*)(logits + (size_t)row * NSEED))[f];
    float4 w;
    w.x = expf(2.f * (l.x - M)) * rS;
    w.y = expf(2.f * (l.y - M)) * rS;
    w.z = expf(2.f * (l.z - M)) * rS;
    w.w = expf(2.f * (l.w - M)) * rS;
    ((float4*)(attn + (size_t)row * NSEED))[f] = w;
}

// chitta gather: 2048 floats per (row,k)
__global__ void gather_kernel(const float* __restrict__ seed,
                              const int* __restrict__ topk_idx,
                              float* __restrict__ chitta)
{
    const int k = blockIdx.x, row = blockIdx.y;
    const int idx = topk_idx[row * KTOP + k];
    const float4* src = (const float4*)(seed + (size_t)idx * D);
    float4* dst = (float4*)(chitta + (size_t)(row * KTOP + k) * D);
#pragma unroll
    for (int j = 0; j < 2; ++j)
        dst[threadIdx.x + j * 256] = src[threadIdx.x + j * 256];
}

extern "C" void kernel_launch(void* const* d_in, const int* in_sizes, int n_in,
                              void* d_out, int out_size, void* d_ws, size_t ws_size,
                              hipStream_t stream)
{
    const float* query = (const float*)d_in[0];
    const int*   types = (const int*)d_in[1];
    const float* seed  = (const float*)d_in[2];
    const float* karma = (const float*)d_in[3];
    const float* vbias = (const float*)d_in[4];
    const float* W1    = (const float*)d_in[5];
    const float* b1    = (const float*)d_in[6];
    const float* W2    = (const float*)d_in[7];
    const float* b2    = (const float*)d_in[8];

    float* ws = (float*)d_ws;
    float* logits = ws + WS_LOGITS;
    float* h      = ws + WS_H;
    float* q2     = ws + WS_Q2;
    float* part   = ws + WS_PART;
    float* cval   = ws + WS_CVAL;
    int*   cidx   = (int*)(ws + WS_CIDX);
    float* cm     = ws + WS_CM;
    float* cs     = ws + WS_CS;
    float* rM     = ws + WS_RM;
    float* rS     = ws + WS_RS;

    // q2 bf16 hi/lo live in their own region (written by fused mlp_reduce L2)
    unsigned short* q2h = (unsigned short*)(ws + WS_Q2HL);   // 64*2048 ushorts
    unsigned short* q2l = q2h + (size_t)B * D;

    // sub-allocations inside PART (free after mlp_reduce layer 2):
    int*   cand2 = (int*)(part + WSP_CAND);                   // 64*64
    float* rvals = part + WSP_RVAL;                           // 64*64
    int*   tidx  = (int*)(part + WSP_TIDX);                   // 64*50

    float* outv   = (float*)d_out;
    float* chitta = outv;                                   // [64][50][2048]
    float* attn   = outv + (size_t)B * KTOP * D;            // [64][50000]
    float* oidxf  = attn + (size_t)B * NSEED;               // [64][50] as float

    // MLP layer 1: 64 n-blocks x 4 k-chunks (K chunk = 512)
    gemm64_kernel<<<256, 256, 0, stream>>>(query, W1, part, D, H, 512, H / 64);
    mlp_reduce_kernel<<<(B * H) / 256, 256, 0, stream>>>(part, b1, h, H, 4, 1, nullptr, nullptr);
    // MLP layer 2: 32 n-blocks x 8 k-chunks (K chunk = 512); fused q2 split
    gemm64_kernel<<<256, 256, 0, stream>>>(h, W2, part, H, D, 512, D / 64);
    mlp_reduce_kernel<<<(B * D) / 256, 256, 0, stream>>>(part, b2, q2, D, 8, 0, q2h, q2l);
    // similarity + gate + bias -> logits (K-step-64, depth-2 pipelined MFMA)
    sims_mfma_kernel<<<(NSEED + 63) / 64, 256, 0, stream>>>(q2h, q2l, seed, karma, types, vbias, logits);
    // per-chunk stats + top-20 candidates
    chunk_topk_kernel<<<B * NCHUNKS, 64, 0, stream>>>(logits, cm, cs, cval, cidx);
    // per-row merge -> (M, 1/S) + top-NCAND candidate set
    merge_topk_kernel<<<B, 256, 0, stream>>>(cm, cs, cval, cidx, rM, rS, cand2);
    // exact fp64 rescore of candidates
    rescore_kernel<<<dim3(NCAND / 4, B), 256, 0, stream>>>(q2, seed, karma, types, vbias, cand2, rvals);
    // final sorted top-50 indices
    final50_kernel<<<B, 64, 0, stream>>>(rvals, cand2, oidxf, tidx);
    // full attention weights
    weights_kernel<<<dim3((NSEED / 4 + 255) / 256, B), 256, 0, stream>>>(logits, rM, rS, attn);
    // retrieved embeddings
    gather_kernel<<<dim3(KTOP, B), 256, 0, stream>>>(seed, tidx, chitta);
}

// Round 7
// 316.284 us; speedup vs baseline: 2.0856x; 1.0746x over previous
//
#include <hip/hip_runtime.h>
#include <math.h>

// Problem constants
#define B 64
#define D 2048
#define H 4096
#define NSEED 50000
#define KTOP 50
#define NCAND 64            // rescored candidates per row
#define CEMIT 20            // candidates emitted per chunk (coverage: P(chunk holds >20 of top-64) ~ 2e-20)
#define NCHUNKS 64          // topk chunks per row
#define CHUNK_SZ 782        // ceil(50000/64)

// ws layout (float offsets)
#define WS_LOGITS   0                         // 64*50000 = 3,200,000 (also MLP partials: max 8*64*4096 = 2.1M)
#define WS_H        3200000                   // 64*4096  = 262,144
#define WS_Q2       (WS_H + B*H)              // 64*2048  = 131,072
#define WS_PART     (WS_Q2 + B*D)             // 1,048,576 (cand/rvals/tidx live here)
#define WS_CVAL     (WS_PART + 1048576)       // 64*64*20 = 81,920 (region sized 262,144)
#define WS_CIDX     (WS_CVAL + 262144)        // ints
#define WS_CM       (WS_CIDX + 262144)        // 4096
#define WS_CS       (WS_CM + 4096)            // 4096
#define WS_RM       (WS_CS + 4096)            // 64
#define WS_RS       (WS_RM + 64)              // 64
#define WS_Q2HL     (WS_RS + 64)              // q2h+q2l: 2*131072 ushorts = 131,072 floats
// sub-allocations inside the PART region:
#define WSP_CAND    200000                    // 64*64 ints
#define WSP_RVAL    220000                    // 64*64 floats
#define WSP_TIDX    240000                    // 64*50 ints

typedef short s16x8 __attribute__((ext_vector_type(8)));
typedef float f32x4 __attribute__((ext_vector_type(4)));

// ---------------------------------------------------------------------------
// bf16 split helpers: x ~= hi + lo, both RNE bf16.
// ---------------------------------------------------------------------------
__device__ __forceinline__ unsigned short bf16_rne(float x)
{
    unsigned int b = __float_as_uint(x);
    b += 0x7FFFu + ((b >> 16) & 1u);
    return (unsigned short)(b >> 16);
}
__device__ __forceinline__ float bf16_tof(unsigned short h)
{
    return __uint_as_float(((unsigned int)h) << 16);
}

// ---------------------------------------------------------------------------
// MLP GEMM, pipelined fp32 (kept fp32 deliberately — q2 accuracy gates the
// topk-index ordering; bf16-split here would exceed the ~6e-6 min rank-gap).
// C_partial[kc][64][N] = A[64][Kc] @ W[Kc][N]
// grid = nBlocks * 8 k-chunks, 256 threads. Tile 64m x 64n, K-step 32.
// Double-buffered LDS, register prefetch, ONE barrier per step.
// Microtile 4m x 4n: per k, 2 x b128 LDS reads feed 16 FMA.
// ---------------------------------------------------------------------------
__global__ __launch_bounds__(256) void gemm64p_kernel(
    const float* __restrict__ A, const float* __restrict__ W,
    float* __restrict__ part, int K, int N, int kcK, int nBlocks)
{
    __shared__ float As[2][32][68];   // [buf][k][m]
    __shared__ float Bs[2][32][68];   // [buf][k][n]

    const int tid = threadIdx.x;
    const int nb = blockIdx.x % nBlocks;
    const int kc = blockIdx.x / nBlocks;
    const int kbeg = kc * kcK;

    const int tidm = tid >> 4;          // 0..15
    const int tidn = tid & 15;          // 0..15
    const int m0 = tidm * 4;
    const int n0 = tidn * 4;

    // staging coords: A tile 64r x 32k (512 float4), B tile 32k x 64n (512 float4)
    const int ar0 = tid >> 3, ac0 = tid & 7;    // + second A float4 at row ar0+32
    const int wr0 = tid >> 4, wc0 = tid & 15;   // + second B float4 at k-row wr0+16

    const float* Aptr0 = A + (size_t)ar0 * K + kbeg + ac0 * 4;
    const float* Aptr1 = A + (size_t)(ar0 + 32) * K + kbeg + ac0 * 4;
    const float* Wptr0 = W + (size_t)(kbeg + wr0) * N + nb * 64 + wc0 * 4;
    const float* Wptr1 = W + (size_t)(kbeg + wr0 + 16) * N + nb * 64 + wc0 * 4;

    float acc[4][4];
#pragma unroll
    for (int i = 0; i < 4; ++i)
#pragma unroll
        for (int j = 0; j < 4; ++j) acc[i][j] = 0.f;

    // prologue: step-0 tiles into registers
    float4 pa0 = *(const float4*)(Aptr0);
    float4 pa1 = *(const float4*)(Aptr1);
    float4 pb0 = *(const float4*)(Wptr0);
    float4 pb1 = *(const float4*)(Wptr1);

    const int nsteps = kcK / 32;
    for (int s = 0; s < nsteps; ++s) {
        const int buf = s & 1;
        // stage from regs (loaded a full step ago)
        As[buf][ac0 * 4 + 0][ar0] = pa0.x;
        As[buf][ac0 * 4 + 1][ar0] = pa0.y;
        As[buf][ac0 * 4 + 2][ar0] = pa0.z;
        As[buf][ac0 * 4 + 3][ar0] = pa0.w;
        As[buf][ac0 * 4 + 0][ar0 + 32] = pa1.x;
        As[buf][ac0 * 4 + 1][ar0 + 32] = pa1.y;
        As[buf][ac0 * 4 + 2][ar0 + 32] = pa1.z;
        As[buf][ac0 * 4 + 3][ar0 + 32] = pa1.w;
        *(float4*)&Bs[buf][wr0][wc0 * 4] = pb0;
        *(float4*)&Bs[buf][wr0 + 16][wc0 * 4] = pb1;
        // prefetch step s+1
        if (s + 1 < nsteps) {
            const int ko = 32 * (s + 1);
            pa0 = *(const float4*)(Aptr0 + ko);
            pa1 = *(const float4*)(Aptr1 + ko);
            pb0 = *(const float4*)(Wptr0 + (size_t)ko * N);
            pb1 = *(const float4*)(Wptr1 + (size_t)ko * N);
        }
        __syncthreads();
#pragma unroll
        for (int kk = 0; kk < 32; ++kk) {
            float4 a = *(const float4*)&As[buf][kk][m0];
            float4 b = *(const float4*)&Bs[buf][kk][n0];
            float av[4] = {a.x, a.y, a.z, a.w};
            float bv[4] = {b.x, b.y, b.z, b.w};
#pragma unroll
            for (int i = 0; i < 4; ++i)
#pragma unroll
                for (int j = 0; j < 4; ++j)
                    acc[i][j] += av[i] * bv[j];
        }
    }

#pragma unroll
    for (int i = 0; i < 4; ++i) {
        float4 v;
        v.x = acc[i][0]; v.y = acc[i][1]; v.z = acc[i][2]; v.w = acc[i][3];
        *(float4*)(part + (size_t)(kc * B + m0 + i) * N + nb * 64 + n0) = v;
    }
}

// Reduce K-chunk partials + bias (+ optional exact GELU).
// When uh/ul are non-null (layer 2), also emits the bf16 hi/lo split of out.
__global__ void mlp_reduce_kernel(const float* __restrict__ part,
                                  const float* __restrict__ bias,
                                  float* __restrict__ out, int N, int nchunks, int gelu,
                                  unsigned short* __restrict__ uh,
                                  unsigned short* __restrict__ ul)
{
    int e = blockIdx.x * 256 + threadIdx.x;   // over B*N
    int b = e / N, j = e - b * N;
    float s = bias[j];
    for (int c = 0; c < nchunks; ++c)
        s += part[(size_t)(c * B + b) * N + j];
    if (gelu)
        s = 0.5f * s * (1.0f + erff(s * 0.70710678118654752f));
    out[e] = s;
    if (uh) {
        unsigned short h = bf16_rne(s);
        uh[e] = h;
        ul[e] = bf16_rne(s - bf16_tof(h));
    }
}

// int64-layout hedge for vritti_types (values 0..4 -> high words all zero)
__device__ __forceinline__ bool types_is_i64(const int* t)
{
    int acc = 0;
#pragma unroll
    for (int j = 0; j < 16; ++j) acc |= t[2 * j + 1];
    return acc == 0;
}

// ---------------------------------------------------------------------------
// sims via split-bf16 MFMA, K-step 64, depth-2 register pipeline (unchanged
// from round 6 — 3 blocks/CU co-resident, ~140 us).
// ---------------------------------------------------------------------------
__global__ __launch_bounds__(256) void sims_mfma_kernel(
    const unsigned short* __restrict__ q2h, const unsigned short* __restrict__ q2l,
    const float* __restrict__ seed,
    const float* __restrict__ karma, const int* __restrict__ types,
    const float* __restrict__ vbias, float* __restrict__ logits)
{
    __shared__ __align__(16) unsigned short Ash[2][64][72];
    __shared__ __align__(16) unsigned short Asl[2][64][72];

    const int tid = threadIdx.x;
    const int n0 = blockIdx.x * 64;
    const int lane = tid & 63;
    const int wv  = tid >> 6;       // 0..3: n-tile of this wave
    const int l15 = lane & 15;
    const int lg  = lane >> 4;      // k-group 0..3

    const int srow = tid >> 2;      // A staging row 0..63
    const int seg  = tid & 3;       // A staging 16-short segment

    const int nrow = n0 + wv * 16 + l15;            // seed row this lane owns
    const bool nvalid = nrow < NSEED;
    const float* brow = seed + (size_t)nrow * D + 8 * lg;
    const size_t aoff = (size_t)srow * D + 16 * seg;

    f32x4 acc[4];
#pragma unroll
    for (int t = 0; t < 4; ++t) acc[t] = (f32x4){0.f, 0.f, 0.f, 0.f};

    // -------- pipeline registers (2 sets, static names) --------
    s16x8 a0ha, a0hb, a0la, a0lb;   // set 0 (even phases)
    s16x8 a1ha, a1hb, a1la, a1lb;   // set 1 (odd phases)
    float4 b00, b01, b02, b03;      // set 0 B: k +[0,4,32,36]
    float4 b10, b11, b12, b13;      // set 1 B

    // prologue: set0 <- phase 0 (kb=0), set1 <- phase 1 (kb=64)
    a0ha = *(const s16x8*)(q2h + aoff);
    a0hb = *(const s16x8*)(q2h + aoff + 8);
    a0la = *(const s16x8*)(q2l + aoff);
    a0lb = *(const s16x8*)(q2l + aoff + 8);
    a1ha = *(const s16x8*)(q2h + aoff + 64);
    a1hb = *(const s16x8*)(q2h + aoff + 72);
    a1la = *(const s16x8*)(q2l + aoff + 64);
    a1lb = *(const s16x8*)(q2l + aoff + 72);
    b00 = b01 = b02 = b03 = make_float4(0.f, 0.f, 0.f, 0.f);
    b10 = b11 = b12 = b13 = make_float4(0.f, 0.f, 0.f, 0.f);
    if (nvalid) {
        b00 = *(const float4*)(brow);      b01 = *(const float4*)(brow + 4);
        b02 = *(const float4*)(brow + 32); b03 = *(const float4*)(brow + 36);
        b10 = *(const float4*)(brow + 64); b11 = *(const float4*)(brow + 68);
        b12 = *(const float4*)(brow + 96); b13 = *(const float4*)(brow + 100);
    }

#define SIMS_CONV(F0, F1, BH, BL)                                          \
    {                                                                      \
        float xs[8] = {F0.x, F0.y, F0.z, F0.w, F1.x, F1.y, F1.z, F1.w};    \
        _Pragma("unroll")                                                  \
        for (int j = 0; j < 8; ++j) {                                      \
            unsigned short hu = bf16_rne(xs[j]);                           \
            BH[j] = (short)hu;                                             \
            BL[j] = (short)bf16_rne(xs[j] - bf16_tof(hu));                 \
        }                                                                  \
    }

#define SIMS_MFMA(BUF, KS, BH, BL)                                         \
    _Pragma("unroll")                                                      \
    for (int t = 0; t < 4; ++t) {                                          \
        s16x8 ah = *(const s16x8*)&Ash[BUF][t * 16 + l15][KS * 32 + 8 * lg]; \
        s16x8 al = *(const s16x8*)&Asl[BUF][t * 16 + l15][KS * 32 + 8 * lg]; \
        acc[t] = __builtin_amdgcn_mfma_f32_16x16x32_bf16(ah, BH, acc[t], 0, 0, 0); \
        acc[t] = __builtin_amdgcn_mfma_f32_16x16x32_bf16(al, BH, acc[t], 0, 0, 0); \
        acc[t] = __builtin_amdgcn_mfma_f32_16x16x32_bf16(ah, BL, acc[t], 0, 0, 0); \
    }

    for (int u = 0; u < 16; ++u) {
        // ================= phase 0: buffer 0, set 0 =================
        *(s16x8*)&Ash[0][srow][16 * seg]     = a0ha;
        *(s16x8*)&Ash[0][srow][16 * seg + 8] = a0hb;
        *(s16x8*)&Asl[0][srow][16 * seg]     = a0la;
        *(s16x8*)&Asl[0][srow][16 * seg + 8] = a0lb;
        float4 n0a = make_float4(0.f, 0.f, 0.f, 0.f), n0b = n0a, n0c = n0a, n0d = n0a;
        if (u < 15) {
            const int kb = 128 * u + 128;          // phase 2u+2
            a0ha = *(const s16x8*)(q2h + aoff + kb);
            a0hb = *(const s16x8*)(q2h + aoff + kb + 8);
            a0la = *(const s16x8*)(q2l + aoff + kb);
            a0lb = *(const s16x8*)(q2l + aoff + kb + 8);
            if (nvalid) {
                n0a = *(const float4*)(brow + kb);      n0b = *(const float4*)(brow + kb + 4);
                n0c = *(const float4*)(brow + kb + 32); n0d = *(const float4*)(brow + kb + 36);
            }
        }
        __syncthreads();
        {
            s16x8 bh, bl;
            SIMS_CONV(b00, b01, bh, bl);
            SIMS_MFMA(0, 0, bh, bl);
            SIMS_CONV(b02, b03, bh, bl);
            SIMS_MFMA(0, 1, bh, bl);
        }
        b00 = n0a; b01 = n0b; b02 = n0c; b03 = n0d;

        // ================= phase 1: buffer 1, set 1 =================
        *(s16x8*)&Ash[1][srow][16 * seg]     = a1ha;
        *(s16x8*)&Ash[1][srow][16 * seg + 8] = a1hb;
        *(s16x8*)&Asl[1][srow][16 * seg]     = a1la;
        *(s16x8*)&Asl[1][srow][16 * seg + 8] = a1lb;
        float4 n1a = make_float4(0.f, 0.f, 0.f, 0.f), n1b = n1a, n1c = n1a, n1d = n1a;
        if (u < 15) {
            const int kb = 128 * u + 192;          // phase 2u+3
            a1ha = *(const s16x8*)(q2h + aoff + kb);
            a1hb = *(const s16x8*)(q2h + aoff + kb + 8);
            a1la = *(const s16x8*)(q2l + aoff + kb);
            a1lb = *(const s16x8*)(q2l + aoff + kb + 8);
            if (nvalid) {
                n1a = *(const float4*)(brow + kb);      n1b = *(const float4*)(brow + kb + 4);
                n1c = *(const float4*)(brow + kb + 32); n1d = *(const float4*)(brow + kb + 36);
            }
        }
        __syncthreads();
        {
            s16x8 bh, bl;
            SIMS_CONV(b10, b11, bh, bl);
            SIMS_MFMA(1, 0, bh, bl);
            SIMS_CONV(b12, b13, bh, bl);
            SIMS_MFMA(1, 1, bh, bl);
        }
        b10 = n1a; b11 = n1b; b12 = n1c; b13 = n1d;
    }
#undef SIMS_CONV
#undef SIMS_MFMA

    // epilogue: gate + vritti bias. D layout: col=lane&15, row=4*lg+reg.
    if (nvalid) {
        const bool i64 = types_is_i64(types);
        float ka = karma[nrow];
        float gate = 1.0f / (1.0f + expf(-(ka + 0.3f) * 10.0f));
        int ty = i64 ? types[2 * nrow] : types[nrow];
        float bias = vbias[ty];
#pragma unroll
        for (int t = 0; t < 4; ++t) {
#pragma unroll
            for (int r = 0; r < 4; ++r) {
                int m = t * 16 + lg * 4 + r;
                logits[(size_t)m * NSEED + nrow] = acc[t][r] * gate + bias;
            }
        }
    }
}

// ---------------------------------------------------------------------------
// Per-(row,chunk): online softmax partial (m,s) + chunk top-CEMIT.
// grid = 64 rows * 64 chunks, 64 threads (1 wave).
// ---------------------------------------------------------------------------
__global__ __launch_bounds__(64) void chunk_topk_kernel(
    const float* __restrict__ logits,
    float* __restrict__ chunk_m, float* __restrict__ chunk_s,
    float* __restrict__ cand_val, int* __restrict__ cand_idx)
{
    const int bid = blockIdx.x;
    const int row = bid >> 6, chunk = bid & 63;
    const int start = chunk * CHUNK_SZ;
    const int end = min(start + CHUNK_SZ, NSEED);
    const int lane = threadIdx.x;
    const float* Lrow = logits + (size_t)row * NSEED;

    float v[13];
#pragma unroll
    for (int j = 0; j < 13; ++j) {
        int e = start + lane + j * 64;
        v[j] = (e < end) ? Lrow[e] : -INFINITY;
    }

    // online (m, s) partial: s = sum exp(2*(l - m))
    float m = v[0];
#pragma unroll
    for (int j = 1; j < 13; ++j) m = fmaxf(m, v[j]);
    float s = 0.f;
#pragma unroll
    for (int j = 0; j < 13; ++j) s += expf(2.f * (v[j] - m));
#pragma unroll
    for (int d = 1; d < 64; d <<= 1) {
        float mo = __shfl_xor(m, d);
        float so = __shfl_xor(s, d);
        float nm = fmaxf(m, mo);
        s = s * expf(2.f * (m - nm)) + so * expf(2.f * (mo - nm));
        m = nm;
    }
    if (lane == 0) { chunk_m[bid] = m; chunk_s[bid] = s; }

    // chunk top-CEMIT via wave-argmax iterations (lower index wins ties)
    for (int it = 0; it < CEMIT; ++it) {
        float bv = v[0]; int bj = 0;
#pragma unroll
        for (int j = 1; j < 13; ++j)
            if (v[j] > bv) { bv = v[j]; bj = j; }
        int bi = start + lane + bj * 64;
#pragma unroll
        for (int d = 1; d < 64; d <<= 1) {
            float ov = __shfl_xor(bv, d);
            int oi = __shfl_xor(bi, d);
            if (ov > bv || (ov == bv && oi < bi)) { bv = ov; bi = oi; }
        }
        if (lane == 0) {
            cand_val[bid * CEMIT + it] = bv;
            cand_idx[bid * CEMIT + it] = bi;
        }
#pragma unroll
        for (int j = 0; j < 13; ++j)
            if (start + lane + j * 64 == bi) v[j] = -INFINITY;
    }
}

// ---------------------------------------------------------------------------
// Per-row merge: 64 (m,s) partials -> (M, 1/S); 1280 candidates -> top-NCAND
// candidate indices (by MFMA logit; candidate set, not final order).
// ---------------------------------------------------------------------------
__global__ __launch_bounds__(256) void merge_topk_kernel(
    const float* __restrict__ chunk_m, const float* __restrict__ chunk_s,
    const float* __restrict__ cand_val, const int* __restrict__ cand_idx,
    float* __restrict__ row_M, float* __restrict__ row_rS,
    int* __restrict__ cand2)
{
    const int row = blockIdx.x;
    const int tid = threadIdx.x;
    const int lane = tid & 63, wave = tid >> 6;
    __shared__ float rv[4];
    __shared__ int ri[4];

    if (wave == 0) {
        float m = chunk_m[row * 64 + lane];
        float s = chunk_s[row * 64 + lane];
#pragma unroll
        for (int d = 1; d < 64; d <<= 1) {
            float mo = __shfl_xor(m, d);
            float so = __shfl_xor(s, d);
            float nm = fmaxf(m, mo);
            s = s * expf(2.f * (m - nm)) + so * expf(2.f * (mo - nm));
            m = nm;
        }
        if (lane == 0) { row_M[row] = m; row_rS[row] = 1.0f / s; }
    }

    float v[5]; int ix[5];
#pragma unroll
    for (int j = 0; j < 5; ++j) {
        int e = tid + j * 256;                      // 1280 = NCHUNKS*CEMIT
        v[j] = cand_val[row * (NCHUNKS * CEMIT) + e];
        ix[j] = cand_idx[row * (NCHUNKS * CEMIT) + e];
    }

    for (int it = 0; it < NCAND; ++it) {
        float bv = v[0]; int bi = ix[0];
#pragma unroll
        for (int j = 1; j < 5; ++j)
            if (v[j] > bv || (v[j] == bv && ix[j] < bi)) { bv = v[j]; bi = ix[j]; }
#pragma unroll
        for (int d = 1; d < 64; d <<= 1) {
            float ov = __shfl_xor(bv, d);
            int oi = __shfl_xor(bi, d);
            if (ov > bv || (ov == bv && oi < bi)) { bv = ov; bi = oi; }
        }
        if (lane == 0) { rv[wave] = bv; ri[wave] = bi; }
        __syncthreads();
        float wv = rv[0]; int wi = ri[0];
#pragma unroll
        for (int w = 1; w < 4; ++w)
            if (rv[w] > wv || (rv[w] == wv && ri[w] < wi)) { wv = rv[w]; wi = ri[w]; }
        __syncthreads();
        if (tid == 0) cand2[row * NCAND + it] = wi;
#pragma unroll
        for (int j = 0; j < 5; ++j)
            if (ix[j] == wi) v[j] = -INFINITY;
    }
}

// ---------------------------------------------------------------------------
// Exact rescore of candidates: fp64 dot(q2[row], seed[idx]) + fp32 gate/bias.
// grid = (NCAND/4, 64 rows), 256 threads = 4 waves (one candidate per wave).
// ---------------------------------------------------------------------------
__global__ __launch_bounds__(256) void rescore_kernel(
    const float* __restrict__ q2, const float* __restrict__ seed,
    const float* __restrict__ karma, const int* __restrict__ types,
    const float* __restrict__ vbias, const int* __restrict__ cand2,
    float* __restrict__ rvals)
{
    const int row = blockIdx.y;
    const int wv = threadIdx.x >> 6, lane = threadIdx.x & 63;
    const int ci = blockIdx.x * 4 + wv;             // 0..NCAND-1
    const int idx = cand2[row * NCAND + ci];
    const float* qrow = q2 + (size_t)row * D;
    const float* srow = seed + (size_t)idx * D;

    double s = 0.0;
#pragma unroll
    for (int i = 0; i < 8; ++i) {
        float4 a = *(const float4*)(qrow + lane * 4 + i * 256);
        float4 b = *(const float4*)(srow + lane * 4 + i * 256);
        s += (double)a.x * (double)b.x + (double)a.y * (double)b.y
           + (double)a.z * (double)b.z + (double)a.w * (double)b.w;
    }
#pragma unroll
    for (int d = 1; d < 64; d <<= 1) s += __shfl_xor(s, d);

    if (lane == 0) {
        float ka = karma[idx];
        float gate = 1.0f / (1.0f + expf(-(ka + 0.3f) * 10.0f));
        bool i64 = types_is_i64(types);
        int ty = i64 ? types[2 * idx] : types[idx];
        rvals[row * NCAND + ci] = (float)s * gate + vbias[ty];
    }
}

// ---------------------------------------------------------------------------
// Final per-row top-50 (sorted desc, lower index on ties) from NCAND rescored.
// grid = 64, 64 threads (1 wave, one candidate per lane).
// ---------------------------------------------------------------------------
__global__ __launch_bounds__(64) void final50_kernel(
    const float* __restrict__ rvals, const int* __restrict__ cand2,
    float* __restrict__ out_idx_f, int* __restrict__ topk_idx)
{
    const int row = blockIdx.x;
    const int lane = threadIdx.x;

    float v = rvals[row * NCAND + lane];
    int ix = cand2[row * NCAND + lane];

    for (int it = 0; it < KTOP; ++it) {
        float bv = v; int bi = ix;
#pragma unroll
        for (int d = 1; d < 64; d <<= 1) {
            float ov = __shfl_xor(bv, d);
            int oi = __shfl_xor(bi, d);
            if (ov > bv || (ov == bv && oi < bi)) { bv = ov; bi = oi; }
        }
        if (lane == 0) {
            out_idx_f[row * KTOP + it] = (float)bi;
            topk_idx[row * KTOP + it] = bi;
        }
        if (ix == bi) v = -INFINITY;
    }
}

// attention weights: w = exp(2*(l - M)) / S
__global__ void weights_kernel(const float* __restrict__ logits,
                               const float* __restrict__ row_M,
                               const float* __restrict__ row_rS,
                               float* __restrict__ attn)
{
    const int row = blockIdx.y;
    const int f = blockIdx.x * 256 + threadIdx.x;
    if (f >= NSEED / 4) return;
    const float M = row_M[row], rS = row_rS[row];
    float4 l = ((const float4*)(logits + (size_t)row * NSEED))[f];
    float4 w;
    w.x = expf(2.f * (l.x - M)) * rS;
    w.y = expf(2.f * (l.y - M)) * rS;
    w.z = expf(2.f * (l.z - M)) * rS;
    w.w = expf(2.f * (l.w - M)) * rS;
    ((float4*)(attn + (size_t)row * NSEED))[f] = w;
}

// chitta gather: 2048 floats per (row,k)
__global__ void gather_kernel(const float* __restrict__ seed,
                              const int* __restrict__ topk_idx,
                              float* __restrict__ chitta)
{
    const int k = blockIdx.x, row = blockIdx.y;
    const int idx = topk_idx[row * KTOP + k];
    const float4* src = (const float4*)(seed + (size_t)idx * D);
    float4* dst = (float4*)(chitta + (size_t)(row * KTOP + k) * D);
#pragma unroll
    for (int j = 0; j < 2; ++j)
        dst[threadIdx.x + j * 256] = src[threadIdx.x + j * 256];
}

extern "C" void kernel_launch(void* const* d_in, const int* in_sizes, int n_in,
                              void* d_out, int out_size, void* d_ws, size_t ws_size,
                              hipStream_t stream)
{
    const float* query = (const float*)d_in[0];
    const int*   types = (const int*)d_in[1];
    const float* seed  = (const float*)d_in[2];
    const float* karma = (const float*)d_in[3];
    const float* vbias = (const float*)d_in[4];
    const float* W1    = (const float*)d_in[5];
    const float* b1    = (const float*)d_in[6];
    const float* W2    = (const float*)d_in[7];
    const float* b2    = (const float*)d_in[8];

    float* ws = (float*)d_ws;
    float* logits = ws + WS_LOGITS;   // also MLP partial buffer (freed before sims)
    float* h      = ws + WS_H;
    float* q2     = ws + WS_Q2;
    float* part   = ws + WS_PART;
    float* cval   = ws + WS_CVAL;
    int*   cidx   = (int*)(ws + WS_CIDX);
    float* cm     = ws + WS_CM;
    float* cs     = ws + WS_CS;
    float* rM     = ws + WS_RM;
    float* rS     = ws + WS_RS;

    // q2 bf16 hi/lo live in their own region (written by fused mlp_reduce L2)
    unsigned short* q2h = (unsigned short*)(ws + WS_Q2HL);   // 64*2048 ushorts
    unsigned short* q2l = q2h + (size_t)B * D;

    // sub-allocations inside PART:
    int*   cand2 = (int*)(part + WSP_CAND);                   // 64*64
    float* rvals = part + WSP_RVAL;                           // 64*64
    int*   tidx  = (int*)(part + WSP_TIDX);                   // 64*50

    float* outv   = (float*)d_out;
    float* chitta = outv;                                   // [64][50][2048]
    float* attn   = outv + (size_t)B * KTOP * D;            // [64][50000]
    float* oidxf  = attn + (size_t)B * NSEED;               // [64][50] as float

    // MLP layer 1: 64 n-blocks x 8 k-chunks (kcK=256) -> 512 blocks, 2/CU
    gemm64p_kernel<<<64 * 8, 256, 0, stream>>>(query, W1, logits, D, H, 256, 64);
    mlp_reduce_kernel<<<(B * H) / 256, 256, 0, stream>>>(logits, b1, h, H, 8, 1, nullptr, nullptr);
    // MLP layer 2: 32 n-blocks x 8 k-chunks (kcK=512) -> 256 blocks; fused q2 split
    gemm64p_kernel<<<32 * 8, 256, 0, stream>>>(h, W2, logits, H, D, 512, 32);
    mlp_reduce_kernel<<<(B * D) / 256, 256, 0, stream>>>(logits, b2, q2, D, 8, 0, q2h, q2l);
    // similarity + gate + bias -> logits (K-step-64, depth-2 pipelined MFMA)
    sims_mfma_kernel<<<(NSEED + 63) / 64, 256, 0, stream>>>(q2h, q2l, seed, karma, types, vbias, logits);
    // per-chunk stats + top-20 candidates
    chunk_topk_kernel<<<B * NCHUNKS, 64, 0, stream>>>(logits, cm, cs, cval, cidx);
    // per-row merge -> (M, 1/S) + top-NCAND candidate set
    merge_topk_kernel<<<B, 256, 0, stream>>>(cm, cs, cval, cidx, rM, rS, cand2);
    // exact fp64 rescore of candidates
    rescore_kernel<<<dim3(NCAND / 4, B), 256, 0, stream>>>(q2, seed, karma, types, vbias, cand2, rvals);
    // final sorted top-50 indices
    final50_kernel<<<B, 64, 0, stream>>>(rvals, cand2, oidxf, tidx);
    // full attention weights
    weights_kernel<<<dim3((NSEED / 4 + 255) / 256, B), 256, 0, stream>>>(logits, rM, rS, attn);
    // retrieved embeddings
    gather_kernel<<<dim3(KTOP, B), 256, 0, stream>>>(seed, tidx, chitta);
}